// Round 3
// baseline (221.727 us; speedup 1.0000x reference)
//
#include <hip/hip_runtime.h>
#include <math.h>

#ifndef M_PI
#define M_PI 3.14159265358979323846
#endif

#define BB 8
#define LL 4096
#define DD 256
#define HH 64

__device__ __forceinline__ float2 cmulf(float2 a, float2 b) {
    return make_float2(a.x*b.x - a.y*b.y, a.x*b.y + a.y*b.x);
}

__device__ __forceinline__ int rev6(int x) {
    return (int)(__brev((unsigned)x) >> 26);
}

// N independent 64-point FFTs across the 64 lanes of a wave, interleaved for
// ILP. DIF radix-2, 6 shuffle stages. Input natural order (lane = index);
// output: value at lane l is X[rev6(l)].
template<bool INV, int N>
__device__ __forceinline__ void fft64n(float2* v, int lane, const float* twc, const float* tws) {
#pragma unroll
    for (int s = 0; s < 6; ++s) {
        const int m = 32 >> s;
        const bool up = (lane & m) != 0;
        const float c  = twc[s];
        const float sn = INV ? -tws[s] : tws[s];
#pragma unroll
        for (int j = 0; j < N; ++j) {
            float ox = __shfl_xor(v[j].x, m, 64);
            float oy = __shfl_xor(v[j].y, m, 64);
            float sx = up ? (ox - v[j].x) : (v[j].x + ox);
            float sy = up ? (oy - v[j].y) : (v[j].y + oy);
            float rx = sx*c - sy*sn;
            float ry = sx*sn + sy*c;
            v[j].x = up ? rx : sx;
            v[j].y = up ? ry : sy;
        }
    }
}

__device__ __forceinline__ float2 woodbury_coef(
    float k00r, float k00i, float k01r, float k01i,
    float k10r, float k10i, float k11r, float k11i, float tc)
{
    // res = k00 - k01*k10/(1+k11);  return (1 + i*tc) * res
    float wr = 1.f + k11r, wi = k11i;
    float winv = __builtin_amdgcn_rcpf(wr*wr + wi*wi);
    float qr = k01r*k10r - k01i*k10i;
    float qi = k01r*k10i + k01i*k10r;
    float dr = (qr*wr + qi*wi) * winv;
    float di = (qi*wr - qr*wi) * winv;
    float rr = k00r - dr, ri = k00i - di;
    return make_float2(rr - tc*ri, tc*rr + ri);
}

// ---------------------------------------------------------------------------
// Kernel 1: Cauchy + Woodbury -> Kf spectrum (lower half only, k in [0,2048]),
// matrix layout Kf[d][k1*64 + k2] for k = k1 + 64*k2. D-term folded in, and
// the conv's 0.5 (two-for-one) and 1/4096 (iFFT) scales pre-applied.
// ---------------------------------------------------------------------------
__global__ __launch_bounds__(256)
void s4_cauchy_kf(const float* __restrict__ lam_ri,
                  const float* __restrict__ P_ri,
                  const float* __restrict__ B_ri,
                  const float* __restrict__ C_ri,
                  const float* __restrict__ Dp,
                  const float* __restrict__ log_delta,
                  float2* __restrict__ Kf)
{
    __shared__ float4 WA[HH];   // {C*B .r, .i, C*P .r, .i}
    __shared__ float4 WB[HH];   // {conj(P)*B .r, .i, |P|^2, -Re(lam)}
    __shared__ float  WC[HH];   // Im(lam)
    const int d   = blockIdx.y;
    const int tid = threadIdx.x;
    if (tid < HH) {
        const int h = tid;
        float br = B_ri[(d*HH + h)*2 + 0], bi = B_ri[(d*HH + h)*2 + 1];
        float cr = C_ri[(d*HH + h)*2 + 0], ci = C_ri[(d*HH + h)*2 + 1];
        float pr = P_ri[h*2 + 0], pi = P_ri[h*2 + 1];
        WA[h] = make_float4(cr*br - ci*bi, cr*bi + ci*br,    // C*B
                            cr*pr - ci*pi, cr*pi + ci*pr);   // C*P
        WB[h] = make_float4(pr*br + pi*bi, pr*bi - pi*br,    // conj(P)*B
                            pr*pr + pi*pi, -lam_ri[h*2+0]);  // |P|^2, -Re(lam)
        WC[h] = lam_ri[h*2+1];
    }
    __syncthreads();
    const int l = blockIdx.x * blockDim.x + tid;
    if (l > 2048) return;
    const float delta = expf(log_delta[d]);
    const float dterm = Dp[d];
    const float SCALE = 0.5f / 4096.f;

    if (l == 2048) {
        // analytic z->-1 limit: at_roots = (delta/2) * sum(C*B), real part
        float sr = 0.f;
        for (int h = 0; h < HH; ++h) sr += WA[h].x;
        Kf[(size_t)d*LL + 32] = make_float2((0.5f*delta*sr + dterm)*SCALE, 0.f);
        return;
    }

    float sn, cs;
    sincosf((float)l * (float)(M_PI/4096.0), &sn, &cs);
    const float t = sn * __builtin_amdgcn_rcpf(cs); // tan(theta/2)
    const float G = -2.f * t * __builtin_amdgcn_rcpf(delta); // g = i*G

    float a00r=0,a00i=0,a01r=0,a01i=0,a10r=0,a10i=0,a11r=0,a11i=0;  // l
    float b00r=0,b00i=0,b01r=0,b01i=0,b10r=0,b10i=0,b11r=0,b11i=0;  // L-l

#pragma unroll 4
    for (int h = 0; h < HH; ++h) {
        const float4 wa = WA[h];
        const float4 wb = WB[h];
        const float  lih = WC[h];
        const float  nr  = wb.w;
        const float  nr2 = nr*nr;
        {
            const float ni  = G - lih;
            const float inv = __builtin_amdgcn_rcpf(nr2 + ni*ni);
            const float rr  = nr*inv, ri = -ni*inv;   // 1/(g - lam)
            a00r += wa.x*rr - wa.y*ri;  a00i += wa.x*ri + wa.y*rr;
            a01r += wa.z*rr - wa.w*ri;  a01i += wa.z*ri + wa.w*rr;
            a10r += wb.x*rr - wb.y*ri;  a10i += wb.x*ri + wb.y*rr;
            a11r += wb.z*rr;            a11i += wb.z*ri;
        }
        {
            const float ni  = -G - lih;
            const float inv = __builtin_amdgcn_rcpf(nr2 + ni*ni);
            const float rr  = nr*inv, ri = -ni*inv;
            b00r += wa.x*rr - wa.y*ri;  b00i += wa.x*ri + wa.y*rr;
            b01r += wa.z*rr - wa.w*ri;  b01i += wa.z*ri + wa.w*rr;
            b10r += wb.x*rr - wb.y*ri;  b10i += wb.x*ri + wb.y*rr;
            b11r += wb.z*rr;            b11i += wb.z*ri;
        }
    }

    // coef = 1 - i*t for l ; 1 + i*t for L-l
    float2 ar1 = woodbury_coef(a00r,a00i,a01r,a01i,a10r,a10i,a11r,a11i, -t);
    float2 ar2 = woodbury_coef(b00r,b00i,b01r,b01i,b10r,b10i,b11r,b11i, +t);

    // Kf[l] = 0.5*(ar(l) + conj(ar(L-l))) + D  (then pre-scale)
    float2 kf = make_float2((0.5f*(ar1.x + ar2.x) + dterm)*SCALE,
                            (0.5f*(ar1.y - ar2.y))*SCALE);
    Kf[(size_t)d*LL + ((l & 63)*64 + (l >> 6))] = kf;
}

// ---------------------------------------------------------------------------
// Kernel 2 (fused): per (b, d-pair): load x[:,2d2:2d2+2] packed complex,
// forward FFT-4096 (four-step 64x64 in LDS, twiddles fused into col passes),
// two-for-one unpack * Kf * repack, inverse FFT, write y directly.
// LDS: flat 64x64 float2 with rotation swizzle (32 KiB -> 5 blocks/CU).
// ---------------------------------------------------------------------------
#define AIDX(r,c) (((r) << 6) + (((c) + (r)) & 63))

__global__ __launch_bounds__(256, 5)
void s4_fftconv(const float* __restrict__ x, const float2* __restrict__ Kf,
                float* __restrict__ y)
{
    __shared__ float2 As[64*64];
    const int tid  = threadIdx.x;
    const int lane = tid & 63;
    const int wid  = tid >> 6;
    // XCD-aware swizzle: 8 consecutive-d2 blocks (which share x/y cache lines)
    // land on the same XCD.
    const int p  = ((blockIdx.x & 7) << 7) | (blockIdx.x >> 3);   // 1024 blocks
    const int b  = p >> 7;
    const int d2 = p & 127;

    const float2* xp = (const float2*)x + ((size_t)b*LL)*(DD/2) + d2;
    float2*       yp = (float2*)y       + ((size_t)b*LL)*(DD/2) + d2;

    // per-lane stage twiddles (forward): exp(-i*pi*j/m), j = lane&(m-1)
    float twc[6], tws[6];
#pragma unroll
    for (int s = 0; s < 6; ++s) {
        int m = 32 >> s;
        int j = lane & (m-1);
        float ang = -(float)M_PI * (float)j / (float)m;
        sincosf(ang, &tws[s], &twc[s]);
    }

    const float PHI = -(float)(2.0*M_PI/4096.0);   // forward sign

    // load packed column: z[n] = x[n][2d2] + i x[n][2d2+1]; n=n1*64+n2 at [n1][n2]
#pragma unroll
    for (int i = 0; i < 16; ++i) {
        int n = tid + 256*i;
        As[AIDX(n>>6, n&63)] = xp[(size_t)n*(DD/2)];
    }
    __syncthreads();

    // forward: column FFTs over n1, fused twiddle W^{-k1*n2}, k1=rev6(lane)
    {
        const int k1 = rev6(lane);
        float2 w, st;
        sincosf(PHI * (float)(k1 * (wid*16)), &w.y,  &w.x);
        sincosf(PHI * (float)k1,              &st.y, &st.x);
#pragma unroll
        for (int cc = 0; cc < 4; ++cc) {
            const int col = wid*16 + cc*4;
            float2 v[4];
#pragma unroll
            for (int j = 0; j < 4; ++j) v[j] = As[AIDX(lane, col+j)];
            fft64n<false,4>(v, lane, twc, tws);
#pragma unroll
            for (int j = 0; j < 4; ++j) {
                As[AIDX(k1, col+j)] = cmulf(v[j], w);
                w = cmulf(w, st);
            }
        }
    }
    __syncthreads();

    // forward: row FFTs over n2 -> X[k1 + 64*k2] at [k1][k2]
#pragma unroll
    for (int cc = 0; cc < 4; ++cc) {
        const int row0 = wid*16 + cc*4;
        float2 v[4];
#pragma unroll
        for (int j = 0; j < 4; ++j) v[j] = As[AIDX(row0+j, lane)];
        fft64n<false,4>(v, lane, twc, tws);
        const int kc = rev6(lane);
#pragma unroll
        for (int j = 0; j < 4; ++j) As[AIDX(row0+j, kc)] = v[j];
    }
    __syncthreads();

    // two-for-one unpack * Kf * repack (0.5 and 1/4096 pre-folded into Kf):
    // Y[k]  = Z[k]*(Ke+Ko) + conj(Z[~k])*(Ke-Ko)
    // Y[~k] = conj( conj(Z[~k])*(Ke+Ko) + Z[k]*(Ke-Ko) )
    {
        const float2* Keb = Kf + (size_t)(2*d2)  *LL;
        const float2* Kob = Kf + (size_t)(2*d2+1)*LL;
#pragma unroll
        for (int i = 0; i < 9; ++i) {
            int k = tid + (i << 8);
            if (k <= 2048) {
                int k1 = k & 63, k2 = k >> 6;
                int m1 = (64 - k1) & 63;
                int m2 = (k1 == 0) ? ((64 - k2) & 63) : (63 - k2);
                float2 Zk = As[AIDX(k1, k2)];
                float2 Zm = As[AIDX(m1, m2)];
                float2 Ke = Keb[k1*64 + k2];
                float2 Ko = Kob[k1*64 + k2];
                float2 S  = make_float2(Ke.x + Ko.x, Ke.y + Ko.y);
                float2 Df = make_float2(Ke.x - Ko.x, Ke.y - Ko.y);
                float2 cZm = make_float2(Zm.x, -Zm.y);
                float2 t0 = cmulf(Zk,  S);
                float2 t1 = cmulf(cZm, Df);
                float2 t2 = cmulf(cZm, S);
                float2 t3 = cmulf(Zk,  Df);
                As[AIDX(k1, k2)] = make_float2(t0.x + t1.x,   t0.y + t1.y);
                As[AIDX(m1, m2)] = make_float2(t2.x + t3.x, -(t2.y + t3.y));
            }
        }
    }
    __syncthreads();

    // inverse: row FFTs over k2
#pragma unroll
    for (int cc = 0; cc < 4; ++cc) {
        const int row0 = wid*16 + cc*4;
        float2 v[4];
#pragma unroll
        for (int j = 0; j < 4; ++j) v[j] = As[AIDX(row0+j, lane)];
        fft64n<true,4>(v, lane, twc, tws);
        const int kc = rev6(lane);
#pragma unroll
        for (int j = 0; j < 4; ++j) As[AIDX(row0+j, kc)] = v[j];
    }
    __syncthreads();

    // inverse: column FFTs over k1, inverse twiddle W^{+lane*col} fused at load
    {
        float2 w, st;
        sincosf(-PHI * (float)(lane * (wid*16)), &w.y,  &w.x);
        sincosf(-PHI * (float)lane,              &st.y, &st.x);
#pragma unroll
        for (int cc = 0; cc < 4; ++cc) {
            const int col = wid*16 + cc*4;
            float2 v[4];
#pragma unroll
            for (int j = 0; j < 4; ++j) {
                v[j] = cmulf(As[AIDX(lane, col+j)], w);
                w = cmulf(w, st);
            }
            fft64n<true,4>(v, lane, twc, tws);
            const int r = rev6(lane);
#pragma unroll
            for (int j = 0; j < 4; ++j) As[AIDX(r, col+j)] = v[j];
        }
    }
    __syncthreads();

    // y_even = Re, y_odd = Im (D*x and all scales already inside Kf)
#pragma unroll
    for (int i = 0; i < 16; ++i) {
        int n = tid + 256*i;
        yp[(size_t)n*(DD/2)] = As[AIDX(n>>6, n&63)];
    }
}

extern "C" void kernel_launch(void* const* d_in, const int* in_sizes, int n_in,
                              void* d_out, int out_size, void* d_ws, size_t ws_size,
                              hipStream_t stream)
{
    (void)in_sizes; (void)n_in; (void)out_size; (void)ws_size;
    const float* x         = (const float*)d_in[0];
    const float* lam_ri    = (const float*)d_in[1];
    const float* P_ri      = (const float*)d_in[2];
    const float* B_ri      = (const float*)d_in[3];
    const float* C_ri      = (const float*)d_in[4];
    const float* Dp        = (const float*)d_in[5];
    const float* log_delta = (const float*)d_in[6];
    float* y = (float*)d_out;

    float2* Kf = (float2*)d_ws;   // DD * LL * 8B = 8 MB

    s4_cauchy_kf<<<dim3(9, DD), 256, 0, stream>>>(lam_ri, P_ri, B_ri, C_ri, Dp, log_delta, Kf);
    s4_fftconv<<<dim3(BB*DD/2), 256, 0, stream>>>(x, Kf, y);
}

// Round 4
// 195.828 us; speedup vs baseline: 1.1323x; 1.1323x over previous
//
#include <hip/hip_runtime.h>
#include <math.h>

#ifndef M_PI
#define M_PI 3.14159265358979323846
#endif

#define BB 8
#define LL 4096
#define DD 256
#define HH 64

__device__ __forceinline__ float2 cmulf(float2 a, float2 b) {
    return make_float2(a.x*b.x - a.y*b.y, a.x*b.y + a.y*b.x);
}

__device__ __forceinline__ int rev6(int x) {
    return (int)(__brev((unsigned)x) >> 26);
}

// N independent 64-point FFTs across the 64 lanes of a wave, interleaved for
// ILP. DIF radix-2, 6 shuffle stages. Input natural order (lane = index);
// output: value at lane l is X[rev6(l)].
template<bool INV, int N>
__device__ __forceinline__ void fft64n(float2* v, int lane, const float* twc, const float* tws) {
#pragma unroll
    for (int s = 0; s < 6; ++s) {
        const int m = 32 >> s;
        const bool up = (lane & m) != 0;
        const float c  = twc[s];
        const float sn = INV ? -tws[s] : tws[s];
#pragma unroll
        for (int j = 0; j < N; ++j) {
            float ox = __shfl_xor(v[j].x, m, 64);
            float oy = __shfl_xor(v[j].y, m, 64);
            float sx = up ? (ox - v[j].x) : (v[j].x + ox);
            float sy = up ? (oy - v[j].y) : (v[j].y + oy);
            float rx = sx*c - sy*sn;
            float ry = sx*sn + sy*c;
            v[j].x = up ? rx : sx;
            v[j].y = up ? ry : sy;
        }
    }
}

__device__ __forceinline__ float2 woodbury_coef(
    float k00r, float k00i, float k01r, float k01i,
    float k10r, float k10i, float k11r, float k11i, float tc)
{
    // res = k00 - k01*k10/(1+k11);  return (1 + i*tc) * res
    float wr = 1.f + k11r, wi = k11i;
    float winv = __builtin_amdgcn_rcpf(wr*wr + wi*wi);
    float qr = k01r*k10r - k01i*k10i;
    float qi = k01r*k10i + k01i*k10r;
    float dr = (qr*wr + qi*wi) * winv;
    float di = (qi*wr - qr*wi) * winv;
    float rr = k00r - dr, ri = k00i - di;
    return make_float2(rr - tc*ri, tc*rr + ri);
}

// ---------------------------------------------------------------------------
// Kernel 1: Cauchy + Woodbury -> Kf spectrum, LINEAR layout Kf[d][k],
// k in [0,2048] (conjugate-symmetric upper half never stored).
// D-term folded in; conv's 0.5 (two-for-one) and 1/4096 (iFFT) pre-applied.
// Stores are coalesced (consecutive l -> consecutive float2).
// ---------------------------------------------------------------------------
__global__ __launch_bounds__(256)
void s4_cauchy_kf(const float* __restrict__ lam_ri,
                  const float* __restrict__ P_ri,
                  const float* __restrict__ B_ri,
                  const float* __restrict__ C_ri,
                  const float* __restrict__ Dp,
                  const float* __restrict__ log_delta,
                  float2* __restrict__ Kf)
{
    __shared__ float4 WA[HH];   // {C*B .r, .i, C*P .r, .i}
    __shared__ float4 WB[HH];   // {conj(P)*B .r, .i, |P|^2, -Re(lam)}
    __shared__ float  WC[HH];   // Im(lam)
    const int d   = blockIdx.y;
    const int tid = threadIdx.x;
    if (tid < HH) {
        const int h = tid;
        float br = B_ri[(d*HH + h)*2 + 0], bi = B_ri[(d*HH + h)*2 + 1];
        float cr = C_ri[(d*HH + h)*2 + 0], ci = C_ri[(d*HH + h)*2 + 1];
        float pr = P_ri[h*2 + 0], pi = P_ri[h*2 + 1];
        WA[h] = make_float4(cr*br - ci*bi, cr*bi + ci*br,    // C*B
                            cr*pr - ci*pi, cr*pi + ci*pr);   // C*P
        WB[h] = make_float4(pr*br + pi*bi, pr*bi - pi*br,    // conj(P)*B
                            pr*pr + pi*pi, -lam_ri[h*2+0]);  // |P|^2, -Re(lam)
        WC[h] = lam_ri[h*2+1];
    }
    __syncthreads();
    const int l = blockIdx.x * blockDim.x + tid;
    if (l > 2048) return;
    const float delta = expf(log_delta[d]);
    const float dterm = Dp[d];
    const float SCALE = 0.5f / 4096.f;

    if (l == 2048) {
        // analytic z->-1 limit: at_roots = (delta/2) * sum(C*B), real part
        float sr = 0.f;
        for (int h = 0; h < HH; ++h) sr += WA[h].x;
        Kf[(size_t)d*LL + 2048] = make_float2((0.5f*delta*sr + dterm)*SCALE, 0.f);
        return;
    }

    float sn, cs;
    sincosf((float)l * (float)(M_PI/4096.0), &sn, &cs);
    const float t = sn * __builtin_amdgcn_rcpf(cs);          // tan(theta/2)
    const float G = -2.f * t * __builtin_amdgcn_rcpf(delta); // g = i*G

    float a00r=0,a00i=0,a01r=0,a01i=0,a10r=0,a10i=0,a11r=0,a11i=0;  // l
    float b00r=0,b00i=0,b01r=0,b01i=0,b10r=0,b10i=0,b11r=0,b11i=0;  // L-l

#pragma unroll 4
    for (int h = 0; h < HH; ++h) {
        const float4 wa = WA[h];
        const float4 wb = WB[h];
        const float  lih = WC[h];
        const float  nr  = wb.w;
        const float  nr2 = nr*nr;
        {
            const float ni  = G - lih;
            const float inv = __builtin_amdgcn_rcpf(nr2 + ni*ni);
            const float rr  = nr*inv, ri = -ni*inv;   // 1/(g - lam)
            a00r += wa.x*rr - wa.y*ri;  a00i += wa.x*ri + wa.y*rr;
            a01r += wa.z*rr - wa.w*ri;  a01i += wa.z*ri + wa.w*rr;
            a10r += wb.x*rr - wb.y*ri;  a10i += wb.x*ri + wb.y*rr;
            a11r += wb.z*rr;            a11i += wb.z*ri;
        }
        {
            const float ni  = -G - lih;
            const float inv = __builtin_amdgcn_rcpf(nr2 + ni*ni);
            const float rr  = nr*inv, ri = -ni*inv;
            b00r += wa.x*rr - wa.y*ri;  b00i += wa.x*ri + wa.y*rr;
            b01r += wa.z*rr - wa.w*ri;  b01i += wa.z*ri + wa.w*rr;
            b10r += wb.x*rr - wb.y*ri;  b10i += wb.x*ri + wb.y*rr;
            b11r += wb.z*rr;            b11i += wb.z*ri;
        }
    }

    // coef = 1 - i*t for l ; 1 + i*t for L-l
    float2 ar1 = woodbury_coef(a00r,a00i,a01r,a01i,a10r,a10i,a11r,a11i, -t);
    float2 ar2 = woodbury_coef(b00r,b00i,b01r,b01i,b10r,b10i,b11r,b11i, +t);

    // Kf[l] = 0.5*(ar(l) + conj(ar(L-l))) + D  (then pre-scale)
    float2 kf = make_float2((0.5f*(ar1.x + ar2.x) + dterm)*SCALE,
                            (0.5f*(ar1.y - ar2.y))*SCALE);
    Kf[(size_t)d*LL + l] = kf;
}

// ---------------------------------------------------------------------------
// Kernel 2 (fused): per (b, d-pair): load x[:,2d2:2d2+2] packed complex,
// forward FFT-4096 (four-step 64x64 in LDS, twiddles fused into col passes),
// two-for-one unpack * Kf * repack, inverse FFT, write y directly.
// LDS: [64][65] float2 padding (round-2 config: uniform 4 blocks/CU keeps
// partner blocks in lockstep -> L2 merges the 8B-per-lane x/y traffic).
// ---------------------------------------------------------------------------
#define AIDX(r,c) ((r)*65 + (c))

__global__ __launch_bounds__(256)
void s4_fftconv(const float* __restrict__ x, const float2* __restrict__ Kf,
                float* __restrict__ y)
{
    __shared__ float2 As[64*65];
    const int tid  = threadIdx.x;
    const int lane = tid & 63;
    const int wid  = tid >> 6;
    // XCD-aware swizzle: 8 consecutive-d2 blocks (which share x/y cache lines)
    // land on the same XCD.
    const int p  = ((blockIdx.x & 7) << 7) | (blockIdx.x >> 3);   // 1024 blocks
    const int b  = p >> 7;
    const int d2 = p & 127;

    const float2* xp = (const float2*)x + ((size_t)b*LL)*(DD/2) + d2;
    float2*       yp = (float2*)y       + ((size_t)b*LL)*(DD/2) + d2;

    // per-lane stage twiddles (forward): exp(-i*pi*j/m), j = lane&(m-1)
    float twc[6], tws[6];
#pragma unroll
    for (int s = 0; s < 6; ++s) {
        int m = 32 >> s;
        int j = lane & (m-1);
        float ang = -(float)M_PI * (float)j / (float)m;
        sincosf(ang, &tws[s], &twc[s]);
    }

    const float PHI = -(float)(2.0*M_PI/4096.0);   // forward sign

    // load packed column: z[n] = x[n][2d2] + i x[n][2d2+1]; n=n1*64+n2 at [n1][n2]
#pragma unroll
    for (int i = 0; i < 16; ++i) {
        int n = tid + 256*i;
        As[AIDX(n>>6, n&63)] = xp[(size_t)n*(DD/2)];
    }
    __syncthreads();

    // forward: column FFTs over n1, fused twiddle W^{-k1*n2}, k1=rev6(lane)
    {
        const int k1 = rev6(lane);
        float2 w, st;
        sincosf(PHI * (float)(k1 * (wid*16)), &w.y,  &w.x);
        sincosf(PHI * (float)k1,              &st.y, &st.x);
#pragma unroll
        for (int cc = 0; cc < 4; ++cc) {
            const int col = wid*16 + cc*4;
            float2 v[4];
#pragma unroll
            for (int j = 0; j < 4; ++j) v[j] = As[AIDX(lane, col+j)];
            fft64n<false,4>(v, lane, twc, tws);
#pragma unroll
            for (int j = 0; j < 4; ++j) {
                As[AIDX(k1, col+j)] = cmulf(v[j], w);
                w = cmulf(w, st);
            }
        }
    }
    __syncthreads();

    // forward: row FFTs over n2 -> X[k1 + 64*k2] at [k1][k2]
#pragma unroll
    for (int cc = 0; cc < 4; ++cc) {
        const int row0 = wid*16 + cc*4;
        float2 v[4];
#pragma unroll
        for (int j = 0; j < 4; ++j) v[j] = As[AIDX(row0+j, lane)];
        fft64n<false,4>(v, lane, twc, tws);
        const int kc = rev6(lane);
#pragma unroll
        for (int j = 0; j < 4; ++j) As[AIDX(row0+j, kc)] = v[j];
    }
    __syncthreads();

    // two-for-one unpack * Kf * repack (0.5 and 1/4096 pre-folded into Kf):
    // Y[k]  = Z[k]*(Ke+Ko) + conj(Z[~k])*(Ke-Ko)
    // Y[~k] = conj( conj(Z[~k])*(Ke+Ko) + Z[k]*(Ke-Ko) )
    // Kf linear in k -> fully coalesced reads.
    {
        const float2* Keb = Kf + (size_t)(2*d2)  *LL;
        const float2* Kob = Kf + (size_t)(2*d2+1)*LL;
#pragma unroll
        for (int i = 0; i < 9; ++i) {
            int k = tid + (i << 8);
            if (k <= 2048) {
                int k1 = k & 63, k2 = k >> 6;
                int m1 = (64 - k1) & 63;
                int m2 = (k1 == 0) ? ((64 - k2) & 63) : (63 - k2);
                float2 Zk = As[AIDX(k1, k2)];
                float2 Zm = As[AIDX(m1, m2)];
                float2 Ke = Keb[k];
                float2 Ko = Kob[k];
                float2 S  = make_float2(Ke.x + Ko.x, Ke.y + Ko.y);
                float2 Df = make_float2(Ke.x - Ko.x, Ke.y - Ko.y);
                float2 cZm = make_float2(Zm.x, -Zm.y);
                float2 t0 = cmulf(Zk,  S);
                float2 t1 = cmulf(cZm, Df);
                float2 t2 = cmulf(cZm, S);
                float2 t3 = cmulf(Zk,  Df);
                As[AIDX(k1, k2)] = make_float2(t0.x + t1.x,   t0.y + t1.y);
                As[AIDX(m1, m2)] = make_float2(t2.x + t3.x, -(t2.y + t3.y));
            }
        }
    }
    __syncthreads();

    // inverse: row FFTs over k2
#pragma unroll
    for (int cc = 0; cc < 4; ++cc) {
        const int row0 = wid*16 + cc*4;
        float2 v[4];
#pragma unroll
        for (int j = 0; j < 4; ++j) v[j] = As[AIDX(row0+j, lane)];
        fft64n<true,4>(v, lane, twc, tws);
        const int kc = rev6(lane);
#pragma unroll
        for (int j = 0; j < 4; ++j) As[AIDX(row0+j, kc)] = v[j];
    }
    __syncthreads();

    // inverse: column FFTs over k1, inverse twiddle W^{+lane*col} fused at load
    {
        float2 w, st;
        sincosf(-PHI * (float)(lane * (wid*16)), &w.y,  &w.x);
        sincosf(-PHI * (float)lane,              &st.y, &st.x);
#pragma unroll
        for (int cc = 0; cc < 4; ++cc) {
            const int col = wid*16 + cc*4;
            float2 v[4];
#pragma unroll
            for (int j = 0; j < 4; ++j) {
                v[j] = cmulf(As[AIDX(lane, col+j)], w);
                w = cmulf(w, st);
            }
            fft64n<true,4>(v, lane, twc, tws);
            const int r = rev6(lane);
#pragma unroll
            for (int j = 0; j < 4; ++j) As[AIDX(r, col+j)] = v[j];
        }
    }
    __syncthreads();

    // y_even = Re, y_odd = Im (D*x and all scales already inside Kf)
#pragma unroll
    for (int i = 0; i < 16; ++i) {
        int n = tid + 256*i;
        yp[(size_t)n*(DD/2)] = As[AIDX(n>>6, n&63)];
    }
}

extern "C" void kernel_launch(void* const* d_in, const int* in_sizes, int n_in,
                              void* d_out, int out_size, void* d_ws, size_t ws_size,
                              hipStream_t stream)
{
    (void)in_sizes; (void)n_in; (void)out_size; (void)ws_size;
    const float* x         = (const float*)d_in[0];
    const float* lam_ri    = (const float*)d_in[1];
    const float* P_ri      = (const float*)d_in[2];
    const float* B_ri      = (const float*)d_in[3];
    const float* C_ri      = (const float*)d_in[4];
    const float* Dp        = (const float*)d_in[5];
    const float* log_delta = (const float*)d_in[6];
    float* y = (float*)d_out;

    float2* Kf = (float2*)d_ws;   // DD * LL * 8B = 8 MB

    s4_cauchy_kf<<<dim3(9, DD), 256, 0, stream>>>(lam_ri, P_ri, B_ri, C_ri, Dp, log_delta, Kf);
    s4_fftconv<<<dim3(BB*DD/2), 256, 0, stream>>>(x, Kf, y);
}

// Round 7
// 178.317 us; speedup vs baseline: 1.2434x; 1.0982x over previous
//
#include <hip/hip_runtime.h>
#include <math.h>

#ifndef M_PI
#define M_PI 3.14159265358979323846
#endif

#define BB 8
#define LL 4096
#define DD 256
#define HH 64

__device__ __forceinline__ float2 cmulf(float2 a, float2 b) {
    return make_float2(a.x*b.x - a.y*b.y, a.x*b.y + a.y*b.x);
}
__device__ __forceinline__ float2 cmul_cs(float2 a, float c, float s) {
    return make_float2(a.x*c - a.y*s, a.x*s + a.y*c);   // a * (c + i s)
}
__device__ __forceinline__ float2 cadd(float2 a, float2 b){return make_float2(a.x+b.x, a.y+b.y);}
__device__ __forceinline__ float2 csub(float2 a, float2 b){return make_float2(a.x-b.x, a.y-b.y);}

// base-4 digit reversal of a 4-bit index: reg slot 4*j0+j1 holds X[j0+4*j1]
#define DR4(i) ((((i)&3)<<2)|((i)>>2))
// spectrum LDS layout (conflict-free for mult + pass3/invpass3)
#define SPW(k) ((((k)>>4)*17) + ((k)&15))

// radix-4 butterfly, in place. SGN=-1 fwd (W4 = -i), +1 inv.
template<int SGN>
__device__ __forceinline__ void r4(float2& a, float2& b, float2& c, float2& d) {
    float2 e0 = cadd(a, c), e1 = csub(a, c);
    float2 o0 = cadd(b, d), o1 = csub(b, d);
    float2 j1 = (SGN < 0) ? make_float2(o1.y, -o1.x) : make_float2(-o1.y, o1.x);
    a = cadd(e0, o0);
    b = cadd(e1, j1);
    c = csub(e0, o0);
    d = csub(e1, j1);
}

// 16-point DFT, natural-order input in v[0..15]; output X[j0+4*j1] in v[4*j0+j1]
// (i.e. v[DR4(k)] = X[k]). Pure registers, no cross-lane ops.
template<int SGN>
__device__ __forceinline__ void fft16(float2 v[16]) {
    const float C16[10] = {1.f, 0.92387953f, 0.70710678f, 0.38268343f, 0.f,
                           -0.38268343f, -0.70710678f, -0.92387953f, -1.f, -0.92387953f};
    const float S16[10] = {0.f, 0.38268343f, 0.70710678f, 0.92387953f, 1.f,
                           0.92387953f, 0.70710678f, 0.38268343f, 0.f, -0.38268343f};
    // stage 1: radix-4 over a1 (stride 4)
#pragma unroll
    for (int a0 = 0; a0 < 4; ++a0)
        r4<SGN>(v[a0], v[a0+4], v[a0+8], v[a0+12]);
    // twiddle: v[a0+4*j0] *= W16^{SGN*a0*j0}
#pragma unroll
    for (int a0 = 1; a0 < 4; ++a0) {
#pragma unroll
        for (int j0 = 1; j0 < 4; ++j0) {
            const int e = a0*j0;
            const float cc = C16[e];
            const float ss = (SGN < 0) ? -S16[e] : S16[e];
            v[a0 + 4*j0] = cmul_cs(v[a0 + 4*j0], cc, ss);
        }
    }
    // stage 2: radix-4 over a0 (stride 1 within each j0 group)
#pragma unroll
    for (int j0 = 0; j0 < 4; ++j0)
        r4<SGN>(v[4*j0+0], v[4*j0+1], v[4*j0+2], v[4*j0+3]);
}

__device__ __forceinline__ float2 woodbury_coef(
    float k00r, float k00i, float k01r, float k01i,
    float k10r, float k10i, float k11r, float k11i, float tc)
{
    // res = k00 - k01*k10/(1+k11);  return (1 + i*tc) * res
    float wr = 1.f + k11r, wi = k11i;
    float winv = __builtin_amdgcn_rcpf(wr*wr + wi*wi);
    float qr = k01r*k10r - k01i*k10i;
    float qi = k01r*k10i + k01i*k10r;
    float dr = (qr*wr + qi*wi) * winv;
    float di = (qi*wr - qr*wi) * winv;
    float rr = k00r - dr, ri = k00i - di;
    return make_float2(rr - tc*ri, tc*rr + ri);
}

// ---------------------------------------------------------------------------
// Kernel 1: Cauchy + Woodbury -> Kf spectrum, LINEAR layout Kf[d][k],
// k in [0,2048]. D-term folded; 0.5 (two-for-one) and 1/4096 (iFFT) folded.
// ---------------------------------------------------------------------------
__global__ __launch_bounds__(256)
void s4_cauchy_kf(const float* __restrict__ lam_ri,
                  const float* __restrict__ P_ri,
                  const float* __restrict__ B_ri,
                  const float* __restrict__ C_ri,
                  const float* __restrict__ Dp,
                  const float* __restrict__ log_delta,
                  float2* __restrict__ Kf)
{
    __shared__ float4 WA[HH];
    __shared__ float4 WB[HH];
    __shared__ float  WC[HH];
    const int d   = blockIdx.y;
    const int tid = threadIdx.x;
    if (tid < HH) {
        const int h = tid;
        float br = B_ri[(d*HH + h)*2 + 0], bi = B_ri[(d*HH + h)*2 + 1];
        float cr = C_ri[(d*HH + h)*2 + 0], ci = C_ri[(d*HH + h)*2 + 1];
        float pr = P_ri[h*2 + 0], pi = P_ri[h*2 + 1];
        WA[h] = make_float4(cr*br - ci*bi, cr*bi + ci*br,
                            cr*pr - ci*pi, cr*pi + ci*pr);
        WB[h] = make_float4(pr*br + pi*bi, pr*bi - pi*br,
                            pr*pr + pi*pi, -lam_ri[h*2+0]);
        WC[h] = lam_ri[h*2+1];
    }
    __syncthreads();
    const int l = blockIdx.x * blockDim.x + tid;
    if (l > 2048) return;
    const float delta = expf(log_delta[d]);
    const float dterm = Dp[d];
    const float SCALE = 0.5f / 4096.f;

    if (l == 2048) {
        float sr = 0.f;
        for (int h = 0; h < HH; ++h) sr += WA[h].x;
        Kf[(size_t)d*LL + 2048] = make_float2((0.5f*delta*sr + dterm)*SCALE, 0.f);
        return;
    }

    float sn, cs;
    sincosf((float)l * (float)(M_PI/4096.0), &sn, &cs);
    const float t = sn * __builtin_amdgcn_rcpf(cs);
    const float G = -2.f * t * __builtin_amdgcn_rcpf(delta);

    float a00r=0,a00i=0,a01r=0,a01i=0,a10r=0,a10i=0,a11r=0,a11i=0;
    float b00r=0,b00i=0,b01r=0,b01i=0,b10r=0,b10i=0,b11r=0,b11i=0;

#pragma unroll 4
    for (int h = 0; h < HH; ++h) {
        const float4 wa = WA[h];
        const float4 wb = WB[h];
        const float  lih = WC[h];
        const float  nr  = wb.w;
        const float  nr2 = nr*nr;
        {
            const float ni  = G - lih;
            const float inv = __builtin_amdgcn_rcpf(nr2 + ni*ni);
            const float rr  = nr*inv, ri = -ni*inv;
            a00r += wa.x*rr - wa.y*ri;  a00i += wa.x*ri + wa.y*rr;
            a01r += wa.z*rr - wa.w*ri;  a01i += wa.z*ri + wa.w*rr;
            a10r += wb.x*rr - wb.y*ri;  a10i += wb.x*ri + wb.y*rr;
            a11r += wb.z*rr;            a11i += wb.z*ri;
        }
        {
            const float ni  = -G - lih;
            const float inv = __builtin_amdgcn_rcpf(nr2 + ni*ni);
            const float rr  = nr*inv, ri = -ni*inv;
            b00r += wa.x*rr - wa.y*ri;  b00i += wa.x*ri + wa.y*rr;
            b01r += wa.z*rr - wa.w*ri;  b01i += wa.z*ri + wa.w*rr;
            b10r += wb.x*rr - wb.y*ri;  b10i += wb.x*ri + wb.y*rr;
            b11r += wb.z*rr;            b11i += wb.z*ri;
        }
    }

    float2 ar1 = woodbury_coef(a00r,a00i,a01r,a01i,a10r,a10i,a11r,a11i, -t);
    float2 ar2 = woodbury_coef(b00r,b00i,b01r,b01i,b10r,b10i,b11r,b11i, +t);

    float2 kf = make_float2((0.5f*(ar1.x + ar2.x) + dterm)*SCALE,
                            (0.5f*(ar1.y - ar2.y))*SCALE);
    Kf[(size_t)d*LL + l] = kf;
}

// ---------------------------------------------------------------------------
// Kernel 2: register radix-16 FFT-4096 (16x16x16), zero cross-lane shuffles.
// n = a*256 + r, r = b*16 + c;  k = k0 + 16*m0 + 256*m1.
// Pass1: FFT16 over a (regs), tw W4096^{r k0}, LDS A[17r + k0].
// Pass2: FFT16 over b, tw W256^{c m0},        LDS B[272k0 + 17c + m0].
// Pass3: FFT16 over c -> spectrum at SPW(k).
// Mult (two-for-one with Kf), then mirrored inverse passes.
// All LDS layouts stride-17-padded: conflict-free per 16-lane quarter.
// ---------------------------------------------------------------------------
__global__ __launch_bounds__(256)
void s4_fftconv(const float* __restrict__ x, const float2* __restrict__ Kf,
                float* __restrict__ y)
{
    __shared__ float2 As[4352];     // 34816 B -> 4 blocks/CU (uniform)
    const int tid = threadIdx.x;
    // XCD-aware swizzle: 8 consecutive-d2 blocks share x/y cache lines
    const int p  = ((blockIdx.x & 7) << 7) | (blockIdx.x >> 3);   // 1024 blocks
    const int b  = p >> 7;
    const int d2 = p & 127;

    const float2* xp = (const float2*)x + ((size_t)b*LL)*(DD/2) + d2;
    float2*       yp = (float2*)y       + ((size_t)b*LL)*(DD/2) + d2;

    float2 v[16];

    // ---- pass 1: thread r = tid; FFT16 over a
    {
        const int r = tid;
#pragma unroll
        for (int a = 0; a < 16; ++a)
            v[a] = xp[(size_t)(a*256 + r)*(DD/2)];
        fft16<-1>(v);
        float2 base; sincosf(-(float)(2.0*M_PI/4096.0)*(float)r, &base.y, &base.x);
        float2 w = make_float2(1.f, 0.f);
#pragma unroll
        for (int k0 = 0; k0 < 16; ++k0) {
            As[17*r + k0] = cmulf(v[DR4(k0)], w);
            w = cmulf(w, base);
        }
    }
    __syncthreads();

    // ---- pass 2: thread (k0 = tid>>4, c = tid&15); FFT16 over b
    {
        const int k0 = tid >> 4, c = tid & 15;
#pragma unroll
        for (int bb = 0; bb < 16; ++bb)
            v[bb] = As[272*bb + 17*c + k0];      // A[17*(b*16+c) + k0]
        __syncthreads();
        fft16<-1>(v);
        float2 base; sincosf(-(float)(2.0*M_PI/256.0)*(float)c, &base.y, &base.x);
        float2 w = make_float2(1.f, 0.f);
#pragma unroll
        for (int m0 = 0; m0 < 16; ++m0) {
            As[272*k0 + 17*c + m0] = cmulf(v[DR4(m0)], w);
            w = cmulf(w, base);
        }
    }
    __syncthreads();

    // ---- pass 3: thread (k0 = tid>>4, m0 = tid&15); FFT16 over c
    {
        const int k0 = tid >> 4, m0 = tid & 15;
#pragma unroll
        for (int c = 0; c < 16; ++c)
            v[c] = As[272*k0 + 17*c + m0];
        __syncthreads();
        fft16<-1>(v);
        const int s17 = 17*m0 + k0;              // SPW(k0+16*m0+256*m1) - 272*m1
#pragma unroll
        for (int m1 = 0; m1 < 16; ++m1)
            As[s17 + 272*m1] = v[DR4(m1)];
    }
    __syncthreads();

    // ---- mult: two-for-one unpack * Kf * repack (scales pre-folded in Kf)
    {
        const float2* Keb = Kf + (size_t)(2*d2)  *LL;
        const float2* Kob = Kf + (size_t)(2*d2+1)*LL;
#pragma unroll
        for (int i = 0; i < 9; ++i) {
            int k = tid + (i << 8);
            if (k <= 2048) {
                int mk = (4096 - k) & 4095;
                float2 Zk = As[SPW(k)];
                float2 Zm = As[SPW(mk)];
                float2 Ke = Keb[k];
                float2 Ko = Kob[k];
                float2 S  = make_float2(Ke.x + Ko.x, Ke.y + Ko.y);
                float2 Df = make_float2(Ke.x - Ko.x, Ke.y - Ko.y);
                float2 cZm = make_float2(Zm.x, -Zm.y);
                float2 t0 = cmulf(Zk,  S);
                float2 t1 = cmulf(cZm, Df);
                float2 t2 = cmulf(cZm, S);
                float2 t3 = cmulf(Zk,  Df);
                As[SPW(k)]  = make_float2(t0.x + t1.x,   t0.y + t1.y);
                As[SPW(mk)] = make_float2(t2.x + t3.x, -(t2.y + t3.y));
            }
        }
    }
    __syncthreads();

    // ---- inv pass 3: thread (k0 = tid>>4, m0 = tid&15); IFFT16 over m1
    {
        const int k0 = tid >> 4, m0 = tid & 15;
        const int s17 = 17*m0 + k0;
#pragma unroll
        for (int m1 = 0; m1 < 16; ++m1)
            v[m1] = As[s17 + 272*m1];
        __syncthreads();
        fft16<1>(v);
        // c-indexed; inverse twiddle cis(+2pi c*m0/256)
        float2 base; sincosf((float)(2.0*M_PI/256.0)*(float)m0, &base.y, &base.x);
        float2 w = make_float2(1.f, 0.f);
#pragma unroll
        for (int c = 0; c < 16; ++c) {
            As[272*k0 + 17*c + m0] = cmulf(v[DR4(c)], w);
            w = cmulf(w, base);
        }
    }
    __syncthreads();

    // ---- inv pass 2: thread (k0 = tid>>4, c = tid&15); IFFT16 over m0
    {
        const int k0 = tid >> 4, c = tid & 15;
#pragma unroll
        for (int m0 = 0; m0 < 16; ++m0)
            v[m0] = As[272*k0 + 17*c + m0];
        __syncthreads();
        fft16<1>(v);
        // b-indexed; inverse twiddle cis(+2pi (b*16+c)*k0/4096)
        float2 w, st;
        sincosf((float)(2.0*M_PI/4096.0)*(float)(c*k0), &w.y, &w.x);
        sincosf((float)(2.0*M_PI/256.0)*(float)k0,      &st.y, &st.x);
#pragma unroll
        for (int bb = 0; bb < 16; ++bb) {
            As[272*bb + 17*c + k0] = cmulf(v[DR4(bb)], w);
            w = cmulf(w, st);
        }
    }
    __syncthreads();

    // ---- inv pass 1: thread r = tid; IFFT16 over k0 -> time samples, store
    {
        const int r = tid;
#pragma unroll
        for (int k0 = 0; k0 < 16; ++k0)
            v[k0] = As[17*r + k0];
        fft16<1>(v);
#pragma unroll
        for (int a = 0; a < 16; ++a)
            yp[(size_t)(a*256 + r)*(DD/2)] = v[DR4(a)];
    }
}

extern "C" void kernel_launch(void* const* d_in, const int* in_sizes, int n_in,
                              void* d_out, int out_size, void* d_ws, size_t ws_size,
                              hipStream_t stream)
{
    (void)in_sizes; (void)n_in; (void)out_size; (void)ws_size;
    const float* x         = (const float*)d_in[0];
    const float* lam_ri    = (const float*)d_in[1];
    const float* P_ri      = (const float*)d_in[2];
    const float* B_ri      = (const float*)d_in[3];
    const float* C_ri      = (const float*)d_in[4];
    const float* Dp        = (const float*)d_in[5];
    const float* log_delta = (const float*)d_in[6];
    float* y = (float*)d_out;

    float2* Kf = (float2*)d_ws;   // DD * LL * 8B = 8 MB

    s4_cauchy_kf<<<dim3(9, DD), 256, 0, stream>>>(lam_ri, P_ri, B_ri, C_ri, Dp, log_delta, Kf);
    s4_fftconv<<<dim3(BB*DD/2), 256, 0, stream>>>(x, Kf, y);
}

// Round 8
// 163.885 us; speedup vs baseline: 1.3529x; 1.0881x over previous
//
#include <hip/hip_runtime.h>
#include <math.h>

#ifndef M_PI
#define M_PI 3.14159265358979323846
#endif

#define BB 8
#define LL 4096
#define DD 256
#define HH 64

__device__ __forceinline__ float2 cmulf(float2 a, float2 b) {
    return make_float2(a.x*b.x - a.y*b.y, a.x*b.y + a.y*b.x);
}
__device__ __forceinline__ float2 cmul_cs(float2 a, float c, float s) {
    return make_float2(a.x*c - a.y*s, a.x*s + a.y*c);   // a * (c + i s)
}
__device__ __forceinline__ float2 cadd(float2 a, float2 b){return make_float2(a.x+b.x, a.y+b.y);}
__device__ __forceinline__ float2 csub(float2 a, float2 b){return make_float2(a.x-b.x, a.y-b.y);}

// base-4 digit reversal of a 4-bit index: reg slot 4*j0+j1 holds X[j0+4*j1]
#define DR4(i) ((((i)&3)<<2)|((i)>>2))
// spectrum LDS layout (conflict-free for mult + pass3/invpass3)
#define SPW(k) ((((k)>>4)*17) + ((k)&15))

// radix-4 butterfly, in place. SGN=-1 fwd (W4 = -i), +1 inv.
template<int SGN>
__device__ __forceinline__ void r4(float2& a, float2& b, float2& c, float2& d) {
    float2 e0 = cadd(a, c), e1 = csub(a, c);
    float2 o0 = cadd(b, d), o1 = csub(b, d);
    float2 j1 = (SGN < 0) ? make_float2(o1.y, -o1.x) : make_float2(-o1.y, o1.x);
    a = cadd(e0, o0);
    b = cadd(e1, j1);
    c = csub(e0, o0);
    d = csub(e1, j1);
}

// 16-point DFT, natural-order input in v[0..15]; output X[j0+4*j1] in v[4*j0+j1]
// (i.e. v[DR4(k)] = X[k]). Pure registers, no cross-lane ops.
template<int SGN>
__device__ __forceinline__ void fft16(float2 v[16]) {
    const float C16[10] = {1.f, 0.92387953f, 0.70710678f, 0.38268343f, 0.f,
                           -0.38268343f, -0.70710678f, -0.92387953f, -1.f, -0.92387953f};
    const float S16[10] = {0.f, 0.38268343f, 0.70710678f, 0.92387953f, 1.f,
                           0.92387953f, 0.70710678f, 0.38268343f, 0.f, -0.38268343f};
#pragma unroll
    for (int a0 = 0; a0 < 4; ++a0)
        r4<SGN>(v[a0], v[a0+4], v[a0+8], v[a0+12]);
#pragma unroll
    for (int a0 = 1; a0 < 4; ++a0) {
#pragma unroll
        for (int j0 = 1; j0 < 4; ++j0) {
            const int e = a0*j0;
            const float cc = C16[e];
            const float ss = (SGN < 0) ? -S16[e] : S16[e];
            v[a0 + 4*j0] = cmul_cs(v[a0 + 4*j0], cc, ss);
        }
    }
#pragma unroll
    for (int j0 = 0; j0 < 4; ++j0)
        r4<SGN>(v[4*j0+0], v[4*j0+1], v[4*j0+2], v[4*j0+3]);
}

__device__ __forceinline__ float2 woodbury_coef(
    float k00r, float k00i, float k01r, float k01i,
    float k10r, float k10i, float k11r, float k11i, float tc)
{
    // res = k00 - k01*k10/(1+k11);  return (1 + i*tc) * res
    float wr = 1.f + k11r, wi = k11i;
    float winv = __builtin_amdgcn_rcpf(wr*wr + wi*wi);
    float qr = k01r*k10r - k01i*k10i;
    float qi = k01r*k10i + k01i*k10r;
    float dr = (qr*wr + qi*wi) * winv;
    float di = (qi*wr - qr*wi) * winv;
    float rr = k00r - dr, ri = k00i - di;
    return make_float2(rr - tc*ri, tc*rr + ri);
}

// ---------------------------------------------------------------------------
// Kernel 1: Cauchy + Woodbury -> Kf spectrum, LINEAR layout Kf[d][k].
// v2: each thread computes TWO l's (l, l+1024) sharing weight loads (2x ILP,
// half LDS traffic); b10/b11 via conjugate-closure of the real-matrix
// spectrum (b10=conj(a10), b11=conj(a11)); one rcp per l (merged +/-G).
// ---------------------------------------------------------------------------
__global__ __launch_bounds__(256)
void s4_cauchy_kf(const float* __restrict__ lam_ri,
                  const float* __restrict__ P_ri,
                  const float* __restrict__ B_ri,
                  const float* __restrict__ C_ri,
                  const float* __restrict__ Dp,
                  const float* __restrict__ log_delta,
                  float2* __restrict__ Kf)
{
    __shared__ float4 WA[HH];   // {C*B r,i, C*P r,i}
    __shared__ float4 WB[HH];   // {conj(P)*B r,i, |P|^2, -Re(lam)}
    __shared__ float  WC[HH];   // Im(lam)
    const int d   = blockIdx.y;
    const int tid = threadIdx.x;
    if (tid < HH) {
        const int h = tid;
        float br = B_ri[(d*HH + h)*2 + 0], bi = B_ri[(d*HH + h)*2 + 1];
        float cr = C_ri[(d*HH + h)*2 + 0], ci = C_ri[(d*HH + h)*2 + 1];
        float pr = P_ri[h*2 + 0], pi = P_ri[h*2 + 1];
        WA[h] = make_float4(cr*br - ci*bi, cr*bi + ci*br,
                            cr*pr - ci*pi, cr*pi + ci*pr);
        WB[h] = make_float4(pr*br + pi*bi, pr*bi - pi*br,
                            pr*pr + pi*pi, -lam_ri[h*2+0]);
        WC[h] = lam_ri[h*2+1];
    }
    __syncthreads();
    const int t0 = blockIdx.x * blockDim.x + tid;   // 0..1023, all active
    const float delta = expf(log_delta[d]);
    const float dterm = Dp[d];
    const float SCALE = 0.5f / 4096.f;

    const int l1 = t0;           // 0..1023
    const int l2 = t0 + 1024;    // 1024..2047

    float sn1, cs1, sn2, cs2;
    sincosf((float)l1 * (float)(M_PI/4096.0), &sn1, &cs1);
    sincosf((float)l2 * (float)(M_PI/4096.0), &sn2, &cs2);
    const float invd = __builtin_amdgcn_rcpf(delta);
    const float tt1 = sn1 * __builtin_amdgcn_rcpf(cs1);
    const float tt2 = sn2 * __builtin_amdgcn_rcpf(cs2);
    const float G1 = -2.f * tt1 * invd;
    const float G2 = -2.f * tt2 * invd;

    // accumulators: a* at +G (00,01,10,11), b* at -G (00,01 only)
    float a00r1=0,a00i1=0,a01r1=0,a01i1=0,a10r1=0,a10i1=0,a11r1=0,a11i1=0;
    float b00r1=0,b00i1=0,b01r1=0,b01i1=0;
    float a00r2=0,a00i2=0,a01r2=0,a01i2=0,a10r2=0,a10i2=0,a11r2=0,a11i2=0;
    float b00r2=0,b00i2=0,b01r2=0,b01i2=0;
    float sr2048 = 0.f;   // for thread 0: sum Re(C*B) -> l=2048 analytic value

#pragma unroll 4
    for (int h = 0; h < HH; ++h) {
        const float4 wa = WA[h];
        const float4 wb = WB[h];
        const float  li = WC[h];
        const float  nr  = wb.w;
        const float  nr2 = nr*nr;
        sr2048 += wa.x;
        // ---- l1
        {
            const float nip = G1 - li, nim = G1 + li;
            const float dp = fmaf(nip, nip, nr2);
            const float dm = fmaf(nim, nim, nr2);
            const float ip = __builtin_amdgcn_rcpf(dp*dm);
            const float invp = dm*ip, invm = dp*ip;
            const float rrp = nr*invp, rip = -nip*invp;  // 1/(iG1 - lam)
            const float rrm = nr*invm, rim =  nim*invm;  // 1/(-iG1 - lam)
            a00r1 += wa.x*rrp - wa.y*rip;  a00i1 += wa.x*rip + wa.y*rrp;
            a01r1 += wa.z*rrp - wa.w*rip;  a01i1 += wa.z*rip + wa.w*rrp;
            a10r1 += wb.x*rrp - wb.y*rip;  a10i1 += wb.x*rip + wb.y*rrp;
            a11r1 += wb.z*rrp;             a11i1 += wb.z*rip;
            b00r1 += wa.x*rrm - wa.y*rim;  b00i1 += wa.x*rim + wa.y*rrm;
            b01r1 += wa.z*rrm - wa.w*rim;  b01i1 += wa.z*rim + wa.w*rrm;
        }
        // ---- l2
        {
            const float nip = G2 - li, nim = G2 + li;
            const float dp = fmaf(nip, nip, nr2);
            const float dm = fmaf(nim, nim, nr2);
            const float ip = __builtin_amdgcn_rcpf(dp*dm);
            const float invp = dm*ip, invm = dp*ip;
            const float rrp = nr*invp, rip = -nip*invp;
            const float rrm = nr*invm, rim =  nim*invm;
            a00r2 += wa.x*rrp - wa.y*rip;  a00i2 += wa.x*rip + wa.y*rrp;
            a01r2 += wa.z*rrp - wa.w*rip;  a01i2 += wa.z*rip + wa.w*rrp;
            a10r2 += wb.x*rrp - wb.y*rip;  a10i2 += wb.x*rip + wb.y*rrp;
            a11r2 += wb.z*rrp;             a11i2 += wb.z*rip;
            b00r2 += wa.x*rrm - wa.y*rim;  b00i2 += wa.x*rim + wa.y*rrm;
            b01r2 += wa.z*rrm - wa.w*rim;  b01i2 += wa.z*rim + wa.w*rrm;
        }
    }

    // conjugate-closure: k10(-G) = conj(k10(+G)), k11(-G) = conj(k11(+G))
    {
        float2 ar1 = woodbury_coef(a00r1,a00i1,a01r1,a01i1,a10r1,a10i1,a11r1,a11i1, -tt1);
        float2 ar2 = woodbury_coef(b00r1,b00i1,b01r1,b01i1,a10r1,-a10i1,a11r1,-a11i1, +tt1);
        float2 kf = make_float2((0.5f*(ar1.x + ar2.x) + dterm)*SCALE,
                                (0.5f*(ar1.y - ar2.y))*SCALE);
        Kf[(size_t)d*LL + l1] = kf;
    }
    {
        float2 ar1 = woodbury_coef(a00r2,a00i2,a01r2,a01i2,a10r2,a10i2,a11r2,a11i2, -tt2);
        float2 ar2 = woodbury_coef(b00r2,b00i2,b01r2,b01i2,a10r2,-a10i2,a11r2,-a11i2, +tt2);
        float2 kf = make_float2((0.5f*(ar1.x + ar2.x) + dterm)*SCALE,
                                (0.5f*(ar1.y - ar2.y))*SCALE);
        Kf[(size_t)d*LL + l2] = kf;
    }
    if (t0 == 0) {
        // analytic z->-1 limit at l=2048: at_roots = (delta/2) * sum(C*B)
        Kf[(size_t)d*LL + 2048] = make_float2((0.5f*delta*sr2048 + dterm)*SCALE, 0.f);
    }
}

// ---------------------------------------------------------------------------
// Kernel 2: register radix-16 FFT-4096 (16x16x16), zero cross-lane shuffles.
// Same structure as round 7 (passed); change: Kf prefetched into registers
// at kernel start (consumed 3 LDS passes later -> global latency hidden).
// ---------------------------------------------------------------------------
__global__ __launch_bounds__(256)
void s4_fftconv(const float* __restrict__ x, const float2* __restrict__ Kf,
                float* __restrict__ y)
{
    __shared__ float2 As[4352];     // 34816 B -> 4 blocks/CU (uniform)
    const int tid = threadIdx.x;
    // XCD-aware swizzle: 8 consecutive-d2 blocks share x/y cache lines
    const int p  = ((blockIdx.x & 7) << 7) | (blockIdx.x >> 3);   // 1024 blocks
    const int b  = p >> 7;
    const int d2 = p & 127;

    const float2* xp = (const float2*)x + ((size_t)b*LL)*(DD/2) + d2;
    float2*       yp = (float2*)y       + ((size_t)b*LL)*(DD/2) + d2;
    const float2* Keb = Kf + (size_t)(2*d2)  *LL;
    const float2* Kob = Kf + (size_t)(2*d2+1)*LL;

    float2 v[16];

    // ---- pass 1 loads (needed first)
    {
        const int r = tid;
#pragma unroll
        for (int a = 0; a < 16; ++a)
            v[a] = xp[(size_t)(a*256 + r)*(DD/2)];
    }
    // ---- Kf register prefetch (used in mult pass, after 3 LDS passes)
    float2 pKe[9], pKo[9];
#pragma unroll
    for (int i = 0; i < 9; ++i) {
        int k = tid + (i << 8); if (k > 2048) k = 2048;   // clamp: inactive lanes
        pKe[i] = Keb[k];
        pKo[i] = Kob[k];
    }

    // ---- pass 1: thread r = tid; FFT16 over a
    {
        const int r = tid;
        fft16<-1>(v);
        float2 base; sincosf(-(float)(2.0*M_PI/4096.0)*(float)r, &base.y, &base.x);
        float2 w = make_float2(1.f, 0.f);
#pragma unroll
        for (int k0 = 0; k0 < 16; ++k0) {
            As[17*r + k0] = cmulf(v[DR4(k0)], w);
            w = cmulf(w, base);
        }
    }
    __syncthreads();

    // ---- pass 2: thread (k0 = tid>>4, c = tid&15); FFT16 over b
    {
        const int k0 = tid >> 4, c = tid & 15;
#pragma unroll
        for (int bb = 0; bb < 16; ++bb)
            v[bb] = As[272*bb + 17*c + k0];      // A[17*(b*16+c) + k0]
        __syncthreads();
        fft16<-1>(v);
        float2 base; sincosf(-(float)(2.0*M_PI/256.0)*(float)c, &base.y, &base.x);
        float2 w = make_float2(1.f, 0.f);
#pragma unroll
        for (int m0 = 0; m0 < 16; ++m0) {
            As[272*k0 + 17*c + m0] = cmulf(v[DR4(m0)], w);
            w = cmulf(w, base);
        }
    }
    __syncthreads();

    // ---- pass 3: thread (k0 = tid>>4, m0 = tid&15); FFT16 over c
    {
        const int k0 = tid >> 4, m0 = tid & 15;
#pragma unroll
        for (int c = 0; c < 16; ++c)
            v[c] = As[272*k0 + 17*c + m0];
        __syncthreads();
        fft16<-1>(v);
        const int s17 = 17*m0 + k0;              // SPW(k0+16*m0+256*m1) - 272*m1
#pragma unroll
        for (int m1 = 0; m1 < 16; ++m1)
            As[s17 + 272*m1] = v[DR4(m1)];
    }
    __syncthreads();

    // ---- mult: two-for-one unpack * Kf * repack (scales pre-folded in Kf)
    {
#pragma unroll
        for (int i = 0; i < 9; ++i) {
            int k = tid + (i << 8);
            if (k <= 2048) {
                int mk = (4096 - k) & 4095;
                float2 Zk = As[SPW(k)];
                float2 Zm = As[SPW(mk)];
                float2 Ke = pKe[i];
                float2 Ko = pKo[i];
                float2 S  = make_float2(Ke.x + Ko.x, Ke.y + Ko.y);
                float2 Df = make_float2(Ke.x - Ko.x, Ke.y - Ko.y);
                float2 cZm = make_float2(Zm.x, -Zm.y);
                float2 t0 = cmulf(Zk,  S);
                float2 t1 = cmulf(cZm, Df);
                float2 t2 = cmulf(cZm, S);
                float2 t3 = cmulf(Zk,  Df);
                As[SPW(k)]  = make_float2(t0.x + t1.x,   t0.y + t1.y);
                As[SPW(mk)] = make_float2(t2.x + t3.x, -(t2.y + t3.y));
            }
        }
    }
    __syncthreads();

    // ---- inv pass 3: thread (k0 = tid>>4, m0 = tid&15); IFFT16 over m1
    {
        const int k0 = tid >> 4, m0 = tid & 15;
        const int s17 = 17*m0 + k0;
#pragma unroll
        for (int m1 = 0; m1 < 16; ++m1)
            v[m1] = As[s17 + 272*m1];
        __syncthreads();
        fft16<1>(v);
        // c-indexed; inverse twiddle cis(+2pi c*m0/256)
        float2 base; sincosf((float)(2.0*M_PI/256.0)*(float)m0, &base.y, &base.x);
        float2 w = make_float2(1.f, 0.f);
#pragma unroll
        for (int c = 0; c < 16; ++c) {
            As[272*k0 + 17*c + m0] = cmulf(v[DR4(c)], w);
            w = cmulf(w, base);
        }
    }
    __syncthreads();

    // ---- inv pass 2: thread (k0 = tid>>4, c = tid&15); IFFT16 over m0
    {
        const int k0 = tid >> 4, c = tid & 15;
#pragma unroll
        for (int m0 = 0; m0 < 16; ++m0)
            v[m0] = As[272*k0 + 17*c + m0];
        __syncthreads();
        fft16<1>(v);
        // b-indexed; inverse twiddle cis(+2pi (b*16+c)*k0/4096)
        float2 w, st;
        sincosf((float)(2.0*M_PI/4096.0)*(float)(c*k0), &w.y, &w.x);
        sincosf((float)(2.0*M_PI/256.0)*(float)k0,      &st.y, &st.x);
#pragma unroll
        for (int bb = 0; bb < 16; ++bb) {
            As[272*bb + 17*c + k0] = cmulf(v[DR4(bb)], w);
            w = cmulf(w, st);
        }
    }
    __syncthreads();

    // ---- inv pass 1: thread r = tid; IFFT16 over k0 -> time samples, store
    {
        const int r = tid;
#pragma unroll
        for (int k0 = 0; k0 < 16; ++k0)
            v[k0] = As[17*r + k0];
        fft16<1>(v);
#pragma unroll
        for (int a = 0; a < 16; ++a)
            yp[(size_t)(a*256 + r)*(DD/2)] = v[DR4(a)];
    }
}

extern "C" void kernel_launch(void* const* d_in, const int* in_sizes, int n_in,
                              void* d_out, int out_size, void* d_ws, size_t ws_size,
                              hipStream_t stream)
{
    (void)in_sizes; (void)n_in; (void)out_size; (void)ws_size;
    const float* x         = (const float*)d_in[0];
    const float* lam_ri    = (const float*)d_in[1];
    const float* P_ri      = (const float*)d_in[2];
    const float* B_ri      = (const float*)d_in[3];
    const float* C_ri      = (const float*)d_in[4];
    const float* Dp        = (const float*)d_in[5];
    const float* log_delta = (const float*)d_in[6];
    float* y = (float*)d_out;

    float2* Kf = (float2*)d_ws;   // DD * LL * 8B = 8 MB

    s4_cauchy_kf<<<dim3(4, DD), 256, 0, stream>>>(lam_ri, P_ri, B_ri, C_ri, Dp, log_delta, Kf);
    s4_fftconv<<<dim3(BB*DD/2), 256, 0, stream>>>(x, Kf, y);
}

// Round 9
// 157.852 us; speedup vs baseline: 1.4046x; 1.0382x over previous
//
#include <hip/hip_runtime.h>
#include <math.h>

#ifndef M_PI
#define M_PI 3.14159265358979323846
#endif

#define BB 8
#define LL 4096
#define DD 256
#define HH 64

__device__ __forceinline__ float2 cmulf(float2 a, float2 b) {
    return make_float2(a.x*b.x - a.y*b.y, a.x*b.y + a.y*b.x);
}
__device__ __forceinline__ float2 cmul_cs(float2 a, float c, float s) {
    return make_float2(a.x*c - a.y*s, a.x*s + a.y*c);   // a * (c + i s)
}
__device__ __forceinline__ float2 cadd(float2 a, float2 b){return make_float2(a.x+b.x, a.y+b.y);}
__device__ __forceinline__ float2 csub(float2 a, float2 b){return make_float2(a.x-b.x, a.y-b.y);}

// base-4 digit reversal of a 4-bit index: reg slot 4*j0+j1 holds X[j0+4*j1]
#define DR4(i) ((((i)&3)<<2)|((i)>>2))
// zero-padding XOR LDS layout: logical (row r in [0,256), col c in [0,16))
// bank-pair = c ^ (r&15): every pass lands at the wave64 minimum (4 lanes/pair)
#define LIDX(r,c) (((r)<<4) + (((c) ^ ((r)&15))))

// radix-4 butterfly, in place. SGN=-1 fwd (W4 = -i), +1 inv.
template<int SGN>
__device__ __forceinline__ void r4(float2& a, float2& b, float2& c, float2& d) {
    float2 e0 = cadd(a, c), e1 = csub(a, c);
    float2 o0 = cadd(b, d), o1 = csub(b, d);
    float2 j1 = (SGN < 0) ? make_float2(o1.y, -o1.x) : make_float2(-o1.y, o1.x);
    a = cadd(e0, o0);
    b = cadd(e1, j1);
    c = csub(e0, o0);
    d = csub(e1, j1);
}

// 16-point DFT, natural-order input in v[0..15]; output X[j0+4*j1] in v[4*j0+j1]
// (i.e. v[DR4(k)] = X[k]). Pure registers, no cross-lane ops.
template<int SGN>
__device__ __forceinline__ void fft16(float2 v[16]) {
    const float C16[10] = {1.f, 0.92387953f, 0.70710678f, 0.38268343f, 0.f,
                           -0.38268343f, -0.70710678f, -0.92387953f, -1.f, -0.92387953f};
    const float S16[10] = {0.f, 0.38268343f, 0.70710678f, 0.92387953f, 1.f,
                           0.92387953f, 0.70710678f, 0.38268343f, 0.f, -0.38268343f};
#pragma unroll
    for (int a0 = 0; a0 < 4; ++a0)
        r4<SGN>(v[a0], v[a0+4], v[a0+8], v[a0+12]);
#pragma unroll
    for (int a0 = 1; a0 < 4; ++a0) {
#pragma unroll
        for (int j0 = 1; j0 < 4; ++j0) {
            const int e = a0*j0;
            const float cc = C16[e];
            const float ss = (SGN < 0) ? -S16[e] : S16[e];
            v[a0 + 4*j0] = cmul_cs(v[a0 + 4*j0], cc, ss);
        }
    }
#pragma unroll
    for (int j0 = 0; j0 < 4; ++j0)
        r4<SGN>(v[4*j0+0], v[4*j0+1], v[4*j0+2], v[4*j0+3]);
}

__device__ __forceinline__ float2 woodbury_coef(
    float k00r, float k00i, float k01r, float k01i,
    float k10r, float k10i, float k11r, float k11i, float tc)
{
    // res = k00 - k01*k10/(1+k11);  return (1 + i*tc) * res
    float wr = 1.f + k11r, wi = k11i;
    float winv = __builtin_amdgcn_rcpf(wr*wr + wi*wi);
    float qr = k01r*k10r - k01i*k10i;
    float qi = k01r*k10i + k01i*k10r;
    float dr = (qr*wr + qi*wi) * winv;
    float di = (qi*wr - qr*wi) * winv;
    float rr = k00r - dr, ri = k00i - di;
    return make_float2(rr - tc*ri, tc*rr + ri);
}

// ---------------------------------------------------------------------------
// Kernel 1: Cauchy + Woodbury -> Kf spectrum, LINEAR layout Kf[d][k].
// (unchanged from round 8 — passed; ~45 us inferred)
// ---------------------------------------------------------------------------
__global__ __launch_bounds__(256)
void s4_cauchy_kf(const float* __restrict__ lam_ri,
                  const float* __restrict__ P_ri,
                  const float* __restrict__ B_ri,
                  const float* __restrict__ C_ri,
                  const float* __restrict__ Dp,
                  const float* __restrict__ log_delta,
                  float2* __restrict__ Kf)
{
    __shared__ float4 WA[HH];   // {C*B r,i, C*P r,i}
    __shared__ float4 WB[HH];   // {conj(P)*B r,i, |P|^2, -Re(lam)}
    __shared__ float  WC[HH];   // Im(lam)
    const int d   = blockIdx.y;
    const int tid = threadIdx.x;
    if (tid < HH) {
        const int h = tid;
        float br = B_ri[(d*HH + h)*2 + 0], bi = B_ri[(d*HH + h)*2 + 1];
        float cr = C_ri[(d*HH + h)*2 + 0], ci = C_ri[(d*HH + h)*2 + 1];
        float pr = P_ri[h*2 + 0], pi = P_ri[h*2 + 1];
        WA[h] = make_float4(cr*br - ci*bi, cr*bi + ci*br,
                            cr*pr - ci*pi, cr*pi + ci*pr);
        WB[h] = make_float4(pr*br + pi*bi, pr*bi - pi*br,
                            pr*pr + pi*pi, -lam_ri[h*2+0]);
        WC[h] = lam_ri[h*2+1];
    }
    __syncthreads();
    const int t0 = blockIdx.x * blockDim.x + tid;   // 0..1023, all active
    const float delta = expf(log_delta[d]);
    const float dterm = Dp[d];
    const float SCALE = 0.5f / 4096.f;

    const int l1 = t0;           // 0..1023
    const int l2 = t0 + 1024;    // 1024..2047

    float sn1, cs1, sn2, cs2;
    sincosf((float)l1 * (float)(M_PI/4096.0), &sn1, &cs1);
    sincosf((float)l2 * (float)(M_PI/4096.0), &sn2, &cs2);
    const float invd = __builtin_amdgcn_rcpf(delta);
    const float tt1 = sn1 * __builtin_amdgcn_rcpf(cs1);
    const float tt2 = sn2 * __builtin_amdgcn_rcpf(cs2);
    const float G1 = -2.f * tt1 * invd;
    const float G2 = -2.f * tt2 * invd;

    float a00r1=0,a00i1=0,a01r1=0,a01i1=0,a10r1=0,a10i1=0,a11r1=0,a11i1=0;
    float b00r1=0,b00i1=0,b01r1=0,b01i1=0;
    float a00r2=0,a00i2=0,a01r2=0,a01i2=0,a10r2=0,a10i2=0,a11r2=0,a11i2=0;
    float b00r2=0,b00i2=0,b01r2=0,b01i2=0;
    float sr2048 = 0.f;

#pragma unroll 4
    for (int h = 0; h < HH; ++h) {
        const float4 wa = WA[h];
        const float4 wb = WB[h];
        const float  li = WC[h];
        const float  nr  = wb.w;
        const float  nr2 = nr*nr;
        sr2048 += wa.x;
        {
            const float nip = G1 - li, nim = G1 + li;
            const float dp = fmaf(nip, nip, nr2);
            const float dm = fmaf(nim, nim, nr2);
            const float ip = __builtin_amdgcn_rcpf(dp*dm);
            const float invp = dm*ip, invm = dp*ip;
            const float rrp = nr*invp, rip = -nip*invp;
            const float rrm = nr*invm, rim =  nim*invm;
            a00r1 += wa.x*rrp - wa.y*rip;  a00i1 += wa.x*rip + wa.y*rrp;
            a01r1 += wa.z*rrp - wa.w*rip;  a01i1 += wa.z*rip + wa.w*rrp;
            a10r1 += wb.x*rrp - wb.y*rip;  a10i1 += wb.x*rip + wb.y*rrp;
            a11r1 += wb.z*rrp;             a11i1 += wb.z*rip;
            b00r1 += wa.x*rrm - wa.y*rim;  b00i1 += wa.x*rim + wa.y*rrm;
            b01r1 += wa.z*rrm - wa.w*rim;  b01i1 += wa.z*rim + wa.w*rrm;
        }
        {
            const float nip = G2 - li, nim = G2 + li;
            const float dp = fmaf(nip, nip, nr2);
            const float dm = fmaf(nim, nim, nr2);
            const float ip = __builtin_amdgcn_rcpf(dp*dm);
            const float invp = dm*ip, invm = dp*ip;
            const float rrp = nr*invp, rip = -nip*invp;
            const float rrm = nr*invm, rim =  nim*invm;
            a00r2 += wa.x*rrp - wa.y*rip;  a00i2 += wa.x*rip + wa.y*rrp;
            a01r2 += wa.z*rrp - wa.w*rip;  a01i2 += wa.z*rip + wa.w*rrp;
            a10r2 += wb.x*rrp - wb.y*rip;  a10i2 += wb.x*rip + wb.y*rrp;
            a11r2 += wb.z*rrp;             a11i2 += wb.z*rip;
            b00r2 += wa.x*rrm - wa.y*rim;  b00i2 += wa.x*rim + wa.y*rrm;
            b01r2 += wa.z*rrm - wa.w*rim;  b01i2 += wa.z*rim + wa.w*rrm;
        }
    }

    {
        float2 ar1 = woodbury_coef(a00r1,a00i1,a01r1,a01i1,a10r1,a10i1,a11r1,a11i1, -tt1);
        float2 ar2 = woodbury_coef(b00r1,b00i1,b01r1,b01i1,a10r1,-a10i1,a11r1,-a11i1, +tt1);
        float2 kf = make_float2((0.5f*(ar1.x + ar2.x) + dterm)*SCALE,
                                (0.5f*(ar1.y - ar2.y))*SCALE);
        Kf[(size_t)d*LL + l1] = kf;
    }
    {
        float2 ar1 = woodbury_coef(a00r2,a00i2,a01r2,a01i2,a10r2,a10i2,a11r2,a11i2, -tt2);
        float2 ar2 = woodbury_coef(b00r2,b00i2,b01r2,b01i2,a10r2,-a10i2,a11r2,-a11i2, +tt2);
        float2 kf = make_float2((0.5f*(ar1.x + ar2.x) + dterm)*SCALE,
                                (0.5f*(ar1.y - ar2.y))*SCALE);
        Kf[(size_t)d*LL + l2] = kf;
    }
    if (t0 == 0) {
        Kf[(size_t)d*LL + 2048] = make_float2((0.5f*delta*sr2048 + dterm)*SCALE, 0.f);
    }
}

// ---------------------------------------------------------------------------
// Kernel 2: register radix-16 FFT-4096, TWO packed sequences per block
// (d-quad: channels 4*d4 .. 4*d4+3). float4 global I/O (16B/lane), shared
// twiddle recurrences between the two sequences, XOR LDS layout (zero pad,
// exactly 64 KiB -> 2 blocks/CU uniform).
// ---------------------------------------------------------------------------
__global__ __launch_bounds__(256)
void s4_fftconv(const float* __restrict__ x, const float2* __restrict__ Kf,
                float* __restrict__ y)
{
    __shared__ float2 As[2][4096];   // 65536 B
    const int tid = threadIdx.x;
    // XCD-aware swizzle over 512 blocks: 8 consecutive-d4 blocks per XCD
    const int p  = ((blockIdx.x & 7) << 6) | (blockIdx.x >> 3);
    const int b  = p >> 6;
    const int d4 = p & 63;

    const float4* xq = (const float4*)x + ((size_t)b*LL)*(DD/4) + d4;
    float4*       yq = (float4*)y       + ((size_t)b*LL)*(DD/4) + d4;
    const float2* KeA = Kf + (size_t)(4*d4 + 0)*LL;
    const float2* KoA = Kf + (size_t)(4*d4 + 1)*LL;
    const float2* KeB = Kf + (size_t)(4*d4 + 2)*LL;
    const float2* KoB = Kf + (size_t)(4*d4 + 3)*LL;

    float2 vA[16], vB[16];

    // ---- pass 1: thread r = tid; FFT16 over a (both seqs)
    {
        const int r = tid;
#pragma unroll
        for (int a = 0; a < 16; ++a) {
            float4 f = xq[(size_t)(a*256 + r)*(DD/4)];
            vA[a] = make_float2(f.x, f.y);
            vB[a] = make_float2(f.z, f.w);
        }
        fft16<-1>(vA);
        fft16<-1>(vB);
        float2 base; sincosf(-(float)(2.0*M_PI/4096.0)*(float)r, &base.y, &base.x);
        float2 w = make_float2(1.f, 0.f);
#pragma unroll
        for (int k0 = 0; k0 < 16; ++k0) {
            const int a0 = LIDX(r, k0);
            As[0][a0] = cmulf(vA[DR4(k0)], w);
            As[1][a0] = cmulf(vB[DR4(k0)], w);
            w = cmulf(w, base);
        }
    }
    __syncthreads();

    // ---- pass 2: thread (k0 = tid>>4, c = tid&15); FFT16 over b
    {
        const int k0 = tid >> 4, c = tid & 15;
#pragma unroll
        for (int bb = 0; bb < 16; ++bb) {
            const int a0 = LIDX(16*bb + c, k0);
            vA[bb] = As[0][a0];
            vB[bb] = As[1][a0];
        }
        __syncthreads();
        fft16<-1>(vA);
        fft16<-1>(vB);
        float2 base; sincosf(-(float)(2.0*M_PI/256.0)*(float)c, &base.y, &base.x);
        float2 w = make_float2(1.f, 0.f);
#pragma unroll
        for (int m0 = 0; m0 < 16; ++m0) {
            const int a0 = LIDX(16*k0 + c, m0);
            As[0][a0] = cmulf(vA[DR4(m0)], w);
            As[1][a0] = cmulf(vB[DR4(m0)], w);
            w = cmulf(w, base);
        }
    }
    __syncthreads();

    // ---- pass 3: thread (k0 = tid>>4, m0 = tid&15); FFT16 over c
    {
        const int k0 = tid >> 4, m0 = tid & 15;
#pragma unroll
        for (int c = 0; c < 16; ++c) {
            const int a0 = LIDX(16*k0 + c, m0);
            vA[c] = As[0][a0];
            vB[c] = As[1][a0];
        }
        __syncthreads();
        fft16<-1>(vA);
        fft16<-1>(vB);
#pragma unroll
        for (int m1 = 0; m1 < 16; ++m1) {
            const int a0 = LIDX(m0 + 16*m1, k0);
            As[0][a0] = vA[DR4(m1)];
            As[1][a0] = vB[DR4(m1)];
        }
    }
    __syncthreads();

    // ---- mult: two-for-one unpack * Kf * repack, per sequence
    {
#pragma unroll
        for (int i = 0; i < 9; ++i) {
            int k = tid + (i << 8);
            if (k <= 2048) {
                const int mk = (4096 - k) & 4095;
                const int ak = LIDX(k>>4,  k&15);
                const int am = LIDX(mk>>4, mk&15);
                {   // seq A
                    float2 Zk = As[0][ak], Zm = As[0][am];
                    float2 Ke = KeA[k],    Ko = KoA[k];
                    float2 S  = make_float2(Ke.x + Ko.x, Ke.y + Ko.y);
                    float2 Df = make_float2(Ke.x - Ko.x, Ke.y - Ko.y);
                    float2 cZm = make_float2(Zm.x, -Zm.y);
                    float2 t0 = cmulf(Zk,  S);
                    float2 t1 = cmulf(cZm, Df);
                    float2 t2 = cmulf(cZm, S);
                    float2 t3 = cmulf(Zk,  Df);
                    As[0][ak] = make_float2(t0.x + t1.x,   t0.y + t1.y);
                    As[0][am] = make_float2(t2.x + t3.x, -(t2.y + t3.y));
                }
                {   // seq B
                    float2 Zk = As[1][ak], Zm = As[1][am];
                    float2 Ke = KeB[k],    Ko = KoB[k];
                    float2 S  = make_float2(Ke.x + Ko.x, Ke.y + Ko.y);
                    float2 Df = make_float2(Ke.x - Ko.x, Ke.y - Ko.y);
                    float2 cZm = make_float2(Zm.x, -Zm.y);
                    float2 t0 = cmulf(Zk,  S);
                    float2 t1 = cmulf(cZm, Df);
                    float2 t2 = cmulf(cZm, S);
                    float2 t3 = cmulf(Zk,  Df);
                    As[1][ak] = make_float2(t0.x + t1.x,   t0.y + t1.y);
                    As[1][am] = make_float2(t2.x + t3.x, -(t2.y + t3.y));
                }
            }
        }
    }
    __syncthreads();

    // ---- inv pass 3: thread (k0 = tid>>4, m0 = tid&15); IFFT16 over m1
    {
        const int k0 = tid >> 4, m0 = tid & 15;
#pragma unroll
        for (int m1 = 0; m1 < 16; ++m1) {
            const int a0 = LIDX(m0 + 16*m1, k0);
            vA[m1] = As[0][a0];
            vB[m1] = As[1][a0];
        }
        __syncthreads();
        fft16<1>(vA);
        fft16<1>(vB);
        float2 base; sincosf((float)(2.0*M_PI/256.0)*(float)m0, &base.y, &base.x);
        float2 w = make_float2(1.f, 0.f);
#pragma unroll
        for (int c = 0; c < 16; ++c) {
            const int a0 = LIDX(16*k0 + c, m0);
            As[0][a0] = cmulf(vA[DR4(c)], w);
            As[1][a0] = cmulf(vB[DR4(c)], w);
            w = cmulf(w, base);
        }
    }
    __syncthreads();

    // ---- inv pass 2: thread (k0 = tid>>4, c = tid&15); IFFT16 over m0
    {
        const int k0 = tid >> 4, c = tid & 15;
#pragma unroll
        for (int m0 = 0; m0 < 16; ++m0) {
            const int a0 = LIDX(16*k0 + c, m0);
            vA[m0] = As[0][a0];
            vB[m0] = As[1][a0];
        }
        __syncthreads();
        fft16<1>(vA);
        fft16<1>(vB);
        float2 w, st;
        sincosf((float)(2.0*M_PI/4096.0)*(float)(c*k0), &w.y, &w.x);
        sincosf((float)(2.0*M_PI/256.0)*(float)k0,      &st.y, &st.x);
#pragma unroll
        for (int bb = 0; bb < 16; ++bb) {
            const int a0 = LIDX(16*bb + c, k0);
            As[0][a0] = cmulf(vA[DR4(bb)], w);
            As[1][a0] = cmulf(vB[DR4(bb)], w);
            w = cmulf(w, st);
        }
    }
    __syncthreads();

    // ---- inv pass 1: thread r = tid; IFFT16 over k0 -> time samples, store
    {
        const int r = tid;
#pragma unroll
        for (int k0 = 0; k0 < 16; ++k0) {
            const int a0 = LIDX(r, k0);
            vA[k0] = As[0][a0];
            vB[k0] = As[1][a0];
        }
        fft16<1>(vA);
        fft16<1>(vB);
#pragma unroll
        for (int a = 0; a < 16; ++a) {
            float2 oa = vA[DR4(a)], ob = vB[DR4(a)];
            yq[(size_t)(a*256 + r)*(DD/4)] = make_float4(oa.x, oa.y, ob.x, ob.y);
        }
    }
}

extern "C" void kernel_launch(void* const* d_in, const int* in_sizes, int n_in,
                              void* d_out, int out_size, void* d_ws, size_t ws_size,
                              hipStream_t stream)
{
    (void)in_sizes; (void)n_in; (void)out_size; (void)ws_size;
    const float* x         = (const float*)d_in[0];
    const float* lam_ri    = (const float*)d_in[1];
    const float* P_ri      = (const float*)d_in[2];
    const float* B_ri      = (const float*)d_in[3];
    const float* C_ri      = (const float*)d_in[4];
    const float* Dp        = (const float*)d_in[5];
    const float* log_delta = (const float*)d_in[6];
    float* y = (float*)d_out;

    float2* Kf = (float2*)d_ws;   // DD * LL * 8B = 8 MB

    s4_cauchy_kf<<<dim3(4, DD), 256, 0, stream>>>(lam_ri, P_ri, B_ri, C_ri, Dp, log_delta, Kf);
    s4_fftconv<<<dim3(BB*DD/4), 256, 0, stream>>>(x, Kf, y);
}

// Round 10
// 156.408 us; speedup vs baseline: 1.4176x; 1.0092x over previous
//
#include <hip/hip_runtime.h>
#include <math.h>

#ifndef M_PI
#define M_PI 3.14159265358979323846
#endif

#define BB 8
#define LL 4096
#define DD 256
#define HH 64

__device__ __forceinline__ float2 cmulf(float2 a, float2 b) {
    return make_float2(a.x*b.x - a.y*b.y, a.x*b.y + a.y*b.x);
}
__device__ __forceinline__ float2 cmul_cs(float2 a, float c, float s) {
    return make_float2(a.x*c - a.y*s, a.x*s + a.y*c);   // a * (c + i s)
}
__device__ __forceinline__ float2 cadd(float2 a, float2 b){return make_float2(a.x+b.x, a.y+b.y);}
__device__ __forceinline__ float2 csub(float2 a, float2 b){return make_float2(a.x-b.x, a.y-b.y);}

// base-4 digit reversal of a 4-bit index: reg slot 4*j0+j1 holds X[j0+4*j1]
#define DR4(i) ((((i)&3)<<2)|((i)>>2))
// zero-padding XOR LDS layout: logical (row r in [0,256), col c in [0,16))
#define LIDX(r,c) (((r)<<4) + (((c) ^ ((r)&15))))

// radix-4 butterfly, in place. SGN=-1 fwd (W4 = -i), +1 inv.
template<int SGN>
__device__ __forceinline__ void r4(float2& a, float2& b, float2& c, float2& d) {
    float2 e0 = cadd(a, c), e1 = csub(a, c);
    float2 o0 = cadd(b, d), o1 = csub(b, d);
    float2 j1 = (SGN < 0) ? make_float2(o1.y, -o1.x) : make_float2(-o1.y, o1.x);
    a = cadd(e0, o0);
    b = cadd(e1, j1);
    c = csub(e0, o0);
    d = csub(e1, j1);
}

// 16-point DFT, natural-order input in v[0..15]; output X[j0+4*j1] in v[4*j0+j1]
template<int SGN>
__device__ __forceinline__ void fft16(float2 v[16]) {
    const float C16[10] = {1.f, 0.92387953f, 0.70710678f, 0.38268343f, 0.f,
                           -0.38268343f, -0.70710678f, -0.92387953f, -1.f, -0.92387953f};
    const float S16[10] = {0.f, 0.38268343f, 0.70710678f, 0.92387953f, 1.f,
                           0.92387953f, 0.70710678f, 0.38268343f, 0.f, -0.38268343f};
#pragma unroll
    for (int a0 = 0; a0 < 4; ++a0)
        r4<SGN>(v[a0], v[a0+4], v[a0+8], v[a0+12]);
#pragma unroll
    for (int a0 = 1; a0 < 4; ++a0) {
#pragma unroll
        for (int j0 = 1; j0 < 4; ++j0) {
            const int e = a0*j0;
            const float cc = C16[e];
            const float ss = (SGN < 0) ? -S16[e] : S16[e];
            v[a0 + 4*j0] = cmul_cs(v[a0 + 4*j0], cc, ss);
        }
    }
#pragma unroll
    for (int j0 = 0; j0 < 4; ++j0)
        r4<SGN>(v[4*j0+0], v[4*j0+1], v[4*j0+2], v[4*j0+3]);
}

__device__ __forceinline__ float2 woodbury_coef(
    float k00r, float k00i, float k01r, float k01i,
    float k10r, float k10i, float k11r, float k11i, float tc)
{
    // res = k00 - k01*k10/(1+k11);  return (1 + i*tc) * res
    float wr = 1.f + k11r, wi = k11i;
    float winv = __builtin_amdgcn_rcpf(wr*wr + wi*wi);
    float qr = k01r*k10r - k01i*k10i;
    float qi = k01r*k10i + k01i*k10r;
    float dr = (qr*wr + qi*wi) * winv;
    float di = (qi*wr - qr*wi) * winv;
    float rr = k00r - dr, ri = k00i - di;
    return make_float2(rr - tc*ri, tc*rr + ri);
}

// ---------------------------------------------------------------------------
// Kernel 1: Cauchy + Woodbury -> Kf spectrum, LINEAR layout Kf[d][k].
// v3: conjugate-pair trick for the ENTIRE -G side: since g = iG is imaginary,
// 1/(-g - lam_h) = conj(1/(g - lam_{p(h)})) with p the conj-pair involution.
// So b00/b01 reuse r_h with permuted weights WAp[h] = WA[p(h)] — no second
// denominator, no second rcp. (b10/b11 already via closure: r8, verified.)
// ---------------------------------------------------------------------------
__global__ __launch_bounds__(256)
void s4_cauchy_kf(const float* __restrict__ lam_ri,
                  const float* __restrict__ P_ri,
                  const float* __restrict__ B_ri,
                  const float* __restrict__ C_ri,
                  const float* __restrict__ Dp,
                  const float* __restrict__ log_delta,
                  float2* __restrict__ Kf)
{
    __shared__ float4 WA[HH];    // {C*B r,i, C*P r,i}
    __shared__ float4 WAp[HH];   // WA at conj-pair partner index
    __shared__ float4 WB[HH];    // {conj(P)*B r,i, |P|^2, -Re(lam)}
    __shared__ float  WC[HH];    // Im(lam)
    const int d   = blockIdx.y;
    const int tid = threadIdx.x;
    if (tid < HH) {
        const int h = tid;
        float br = B_ri[(d*HH + h)*2 + 0], bi = B_ri[(d*HH + h)*2 + 1];
        float cr = C_ri[(d*HH + h)*2 + 0], ci = C_ri[(d*HH + h)*2 + 1];
        float pr = P_ri[h*2 + 0], pi = P_ri[h*2 + 1];
        WA[h] = make_float4(cr*br - ci*bi, cr*bi + ci*br,
                            cr*pr - ci*pi, cr*pi + ci*pr);
        WB[h] = make_float4(pr*br + pi*bi, pr*bi - pi*br,
                            pr*pr + pi*pi, -lam_ri[h*2+0]);
        WC[h] = lam_ri[h*2+1];
    }
    __syncthreads();
    if (tid < HH) {
        // find conj-pair partner: argmin_j |lam_j - conj(lam_tid)|
        const float nrh = WB[tid].w;   // -Re(lam_h)
        const float lih = WC[tid];
        int best = 0; float bd = 3.0e38f;
        for (int j = 0; j < HH; ++j) {
            float dr = nrh - WB[j].w;          // Re_j - Re_h
            float di = WC[j] + lih;            // Im_j + Im_h
            float dist = dr*dr + di*di;
            if (dist < bd) { bd = dist; best = j; }
        }
        WAp[tid] = WA[best];
    }
    __syncthreads();
    const int t0 = blockIdx.x * blockDim.x + tid;   // 0..1023, all active
    const float delta = expf(log_delta[d]);
    const float dterm = Dp[d];
    const float SCALE = 0.5f / 4096.f;

    const int l1 = t0;           // 0..1023
    const int l2 = t0 + 1024;    // 1024..2047

    float sn1, cs1, sn2, cs2;
    sincosf((float)l1 * (float)(M_PI/4096.0), &sn1, &cs1);
    sincosf((float)l2 * (float)(M_PI/4096.0), &sn2, &cs2);
    const float invd = __builtin_amdgcn_rcpf(delta);
    const float tt1 = sn1 * __builtin_amdgcn_rcpf(cs1);
    const float tt2 = sn2 * __builtin_amdgcn_rcpf(cs2);
    const float G1 = -2.f * tt1 * invd;
    const float G2 = -2.f * tt2 * invd;

    float a00r1=0,a00i1=0,a01r1=0,a01i1=0,a10r1=0,a10i1=0,a11r1=0,a11i1=0;
    float b00r1=0,b00i1=0,b01r1=0,b01i1=0;
    float a00r2=0,a00i2=0,a01r2=0,a01i2=0,a10r2=0,a10i2=0,a11r2=0,a11i2=0;
    float b00r2=0,b00i2=0,b01r2=0,b01i2=0;
    float sr2048 = 0.f;

#pragma unroll 4
    for (int h = 0; h < HH; ++h) {
        const float4 wa  = WA[h];
        const float4 wap = WAp[h];
        const float4 wb  = WB[h];
        const float  li  = WC[h];
        const float  nr  = wb.w;
        const float  nr2 = nr*nr;
        sr2048 += wa.x;
        // ---- l1: r = 1/(iG1 - lam_h); b-sums use conj(r) with permuted weights
        {
            const float nip = G1 - li;
            const float invp = __builtin_amdgcn_rcpf(fmaf(nip, nip, nr2));
            const float rr = nr*invp, ri = -nip*invp;
            a00r1 += wa.x*rr - wa.y*ri;   a00i1 += wa.x*ri + wa.y*rr;
            a01r1 += wa.z*rr - wa.w*ri;   a01i1 += wa.z*ri + wa.w*rr;
            a10r1 += wb.x*rr - wb.y*ri;   a10i1 += wb.x*ri + wb.y*rr;
            a11r1 += wb.z*rr;             a11i1 += wb.z*ri;
            b00r1 += wap.x*rr + wap.y*ri; b00i1 += wap.y*rr - wap.x*ri;
            b01r1 += wap.z*rr + wap.w*ri; b01i1 += wap.w*rr - wap.z*ri;
        }
        // ---- l2
        {
            const float nip = G2 - li;
            const float invp = __builtin_amdgcn_rcpf(fmaf(nip, nip, nr2));
            const float rr = nr*invp, ri = -nip*invp;
            a00r2 += wa.x*rr - wa.y*ri;   a00i2 += wa.x*ri + wa.y*rr;
            a01r2 += wa.z*rr - wa.w*ri;   a01i2 += wa.z*ri + wa.w*rr;
            a10r2 += wb.x*rr - wb.y*ri;   a10i2 += wb.x*ri + wb.y*rr;
            a11r2 += wb.z*rr;             a11i2 += wb.z*ri;
            b00r2 += wap.x*rr + wap.y*ri; b00i2 += wap.y*rr - wap.x*ri;
            b01r2 += wap.z*rr + wap.w*ri; b01i2 += wap.w*rr - wap.z*ri;
        }
    }

    {
        float2 ar1 = woodbury_coef(a00r1,a00i1,a01r1,a01i1,a10r1,a10i1,a11r1,a11i1, -tt1);
        float2 ar2 = woodbury_coef(b00r1,b00i1,b01r1,b01i1,a10r1,-a10i1,a11r1,-a11i1, +tt1);
        float2 kf = make_float2((0.5f*(ar1.x + ar2.x) + dterm)*SCALE,
                                (0.5f*(ar1.y - ar2.y))*SCALE);
        Kf[(size_t)d*LL + l1] = kf;
    }
    {
        float2 ar1 = woodbury_coef(a00r2,a00i2,a01r2,a01i2,a10r2,a10i2,a11r2,a11i2, -tt2);
        float2 ar2 = woodbury_coef(b00r2,b00i2,b01r2,b01i2,a10r2,-a10i2,a11r2,-a11i2, +tt2);
        float2 kf = make_float2((0.5f*(ar1.x + ar2.x) + dterm)*SCALE,
                                (0.5f*(ar1.y - ar2.y))*SCALE);
        Kf[(size_t)d*LL + l2] = kf;
    }
    if (t0 == 0) {
        Kf[(size_t)d*LL + 2048] = make_float2((0.5f*delta*sr2048 + dterm)*SCALE, 0.f);
    }
}

// ---------------------------------------------------------------------------
// Kernel 2: register radix-16 FFT-4096, TWO packed sequences per block.
// v2: ALL Kf mult coefficients prefetched into registers at kernel start
// (occupancy is LDS-capped at 2 blocks/CU, so VGPRs up to 256 are free;
// __launch_bounds__(256,2) permits the allocation). Removes the mid-kernel
// global-load stall at the mult phase.
// ---------------------------------------------------------------------------
__global__ __launch_bounds__(256, 2)
void s4_fftconv(const float* __restrict__ x, const float2* __restrict__ Kf,
                float* __restrict__ y)
{
    __shared__ float2 As[2][4096];   // 65536 B
    const int tid = threadIdx.x;
    // XCD-aware swizzle over 512 blocks: 8 consecutive-d4 blocks per XCD
    const int p  = ((blockIdx.x & 7) << 6) | (blockIdx.x >> 3);
    const int b  = p >> 6;
    const int d4 = p & 63;

    const float4* xq = (const float4*)x + ((size_t)b*LL)*(DD/4) + d4;
    float4*       yq = (float4*)y       + ((size_t)b*LL)*(DD/4) + d4;
    const float2* KeA = Kf + (size_t)(4*d4 + 0)*LL;
    const float2* KoA = Kf + (size_t)(4*d4 + 1)*LL;
    const float2* KeB = Kf + (size_t)(4*d4 + 2)*LL;
    const float2* KoB = Kf + (size_t)(4*d4 + 3)*LL;

    float2 vA[16], vB[16];

    // ---- global loads: x first (needed by pass 1), then the full Kf
    // prefetch (consumed at mult, 3 LDS passes later -> latency fully hidden)
    {
        const int r = tid;
#pragma unroll
        for (int a = 0; a < 16; ++a) {
            float4 f = xq[(size_t)(a*256 + r)*(DD/4)];
            vA[a] = make_float2(f.x, f.y);
            vB[a] = make_float2(f.z, f.w);
        }
    }
    float2 pKeA[9], pKoA[9], pKeB[9], pKoB[9];
#pragma unroll
    for (int i = 0; i < 9; ++i) {
        int k = tid + (i << 8); if (k > 2048) k = 2048;   // clamp inactive
        pKeA[i] = KeA[k];  pKoA[i] = KoA[k];
        pKeB[i] = KeB[k];  pKoB[i] = KoB[k];
    }

    // ---- pass 1: thread r = tid; FFT16 over a (both seqs)
    {
        const int r = tid;
        fft16<-1>(vA);
        fft16<-1>(vB);
        float2 base; sincosf(-(float)(2.0*M_PI/4096.0)*(float)r, &base.y, &base.x);
        float2 w = make_float2(1.f, 0.f);
#pragma unroll
        for (int k0 = 0; k0 < 16; ++k0) {
            const int a0 = LIDX(r, k0);
            As[0][a0] = cmulf(vA[DR4(k0)], w);
            As[1][a0] = cmulf(vB[DR4(k0)], w);
            w = cmulf(w, base);
        }
    }
    __syncthreads();

    // ---- pass 2: thread (k0 = tid>>4, c = tid&15); FFT16 over b
    {
        const int k0 = tid >> 4, c = tid & 15;
#pragma unroll
        for (int bb = 0; bb < 16; ++bb) {
            const int a0 = LIDX(16*bb + c, k0);
            vA[bb] = As[0][a0];
            vB[bb] = As[1][a0];
        }
        __syncthreads();
        fft16<-1>(vA);
        fft16<-1>(vB);
        float2 base; sincosf(-(float)(2.0*M_PI/256.0)*(float)c, &base.y, &base.x);
        float2 w = make_float2(1.f, 0.f);
#pragma unroll
        for (int m0 = 0; m0 < 16; ++m0) {
            const int a0 = LIDX(16*k0 + c, m0);
            As[0][a0] = cmulf(vA[DR4(m0)], w);
            As[1][a0] = cmulf(vB[DR4(m0)], w);
            w = cmulf(w, base);
        }
    }
    __syncthreads();

    // ---- pass 3: thread (k0 = tid>>4, m0 = tid&15); FFT16 over c
    {
        const int k0 = tid >> 4, m0 = tid & 15;
#pragma unroll
        for (int c = 0; c < 16; ++c) {
            const int a0 = LIDX(16*k0 + c, m0);
            vA[c] = As[0][a0];
            vB[c] = As[1][a0];
        }
        __syncthreads();
        fft16<-1>(vA);
        fft16<-1>(vB);
#pragma unroll
        for (int m1 = 0; m1 < 16; ++m1) {
            const int a0 = LIDX(m0 + 16*m1, k0);
            As[0][a0] = vA[DR4(m1)];
            As[1][a0] = vB[DR4(m1)];
        }
    }
    __syncthreads();

    // ---- mult: two-for-one unpack * Kf * repack, per sequence (regs only)
    {
#pragma unroll
        for (int i = 0; i < 9; ++i) {
            int k = tid + (i << 8);
            if (k <= 2048) {
                const int mk = (4096 - k) & 4095;
                const int ak = LIDX(k>>4,  k&15);
                const int am = LIDX(mk>>4, mk&15);
                {   // seq A
                    float2 Zk = As[0][ak], Zm = As[0][am];
                    float2 Ke = pKeA[i],   Ko = pKoA[i];
                    float2 S  = make_float2(Ke.x + Ko.x, Ke.y + Ko.y);
                    float2 Df = make_float2(Ke.x - Ko.x, Ke.y - Ko.y);
                    float2 cZm = make_float2(Zm.x, -Zm.y);
                    float2 t0 = cmulf(Zk,  S);
                    float2 t1 = cmulf(cZm, Df);
                    float2 t2 = cmulf(cZm, S);
                    float2 t3 = cmulf(Zk,  Df);
                    As[0][ak] = make_float2(t0.x + t1.x,   t0.y + t1.y);
                    As[0][am] = make_float2(t2.x + t3.x, -(t2.y + t3.y));
                }
                {   // seq B
                    float2 Zk = As[1][ak], Zm = As[1][am];
                    float2 Ke = pKeB[i],   Ko = pKoB[i];
                    float2 S  = make_float2(Ke.x + Ko.x, Ke.y + Ko.y);
                    float2 Df = make_float2(Ke.x - Ko.x, Ke.y - Ko.y);
                    float2 cZm = make_float2(Zm.x, -Zm.y);
                    float2 t0 = cmulf(Zk,  S);
                    float2 t1 = cmulf(cZm, Df);
                    float2 t2 = cmulf(cZm, S);
                    float2 t3 = cmulf(Zk,  Df);
                    As[1][ak] = make_float2(t0.x + t1.x,   t0.y + t1.y);
                    As[1][am] = make_float2(t2.x + t3.x, -(t2.y + t3.y));
                }
            }
        }
    }
    __syncthreads();

    // ---- inv pass 3: thread (k0 = tid>>4, m0 = tid&15); IFFT16 over m1
    {
        const int k0 = tid >> 4, m0 = tid & 15;
#pragma unroll
        for (int m1 = 0; m1 < 16; ++m1) {
            const int a0 = LIDX(m0 + 16*m1, k0);
            vA[m1] = As[0][a0];
            vB[m1] = As[1][a0];
        }
        __syncthreads();
        fft16<1>(vA);
        fft16<1>(vB);
        float2 base; sincosf((float)(2.0*M_PI/256.0)*(float)m0, &base.y, &base.x);
        float2 w = make_float2(1.f, 0.f);
#pragma unroll
        for (int c = 0; c < 16; ++c) {
            const int a0 = LIDX(16*k0 + c, m0);
            As[0][a0] = cmulf(vA[DR4(c)], w);
            As[1][a0] = cmulf(vB[DR4(c)], w);
            w = cmulf(w, base);
        }
    }
    __syncthreads();

    // ---- inv pass 2: thread (k0 = tid>>4, c = tid&15); IFFT16 over m0
    {
        const int k0 = tid >> 4, c = tid & 15;
#pragma unroll
        for (int m0 = 0; m0 < 16; ++m0) {
            const int a0 = LIDX(16*k0 + c, m0);
            vA[m0] = As[0][a0];
            vB[m0] = As[1][a0];
        }
        __syncthreads();
        fft16<1>(vA);
        fft16<1>(vB);
        float2 w, st;
        sincosf((float)(2.0*M_PI/4096.0)*(float)(c*k0), &w.y, &w.x);
        sincosf((float)(2.0*M_PI/256.0)*(float)k0,      &st.y, &st.x);
#pragma unroll
        for (int bb = 0; bb < 16; ++bb) {
            const int a0 = LIDX(16*bb + c, k0);
            As[0][a0] = cmulf(vA[DR4(bb)], w);
            As[1][a0] = cmulf(vB[DR4(bb)], w);
            w = cmulf(w, st);
        }
    }
    __syncthreads();

    // ---- inv pass 1: thread r = tid; IFFT16 over k0 -> time samples, store
    {
        const int r = tid;
#pragma unroll
        for (int k0 = 0; k0 < 16; ++k0) {
            const int a0 = LIDX(r, k0);
            vA[k0] = As[0][a0];
            vB[k0] = As[1][a0];
        }
        fft16<1>(vA);
        fft16<1>(vB);
#pragma unroll
        for (int a = 0; a < 16; ++a) {
            float2 oa = vA[DR4(a)], ob = vB[DR4(a)];
            yq[(size_t)(a*256 + r)*(DD/4)] = make_float4(oa.x, oa.y, ob.x, ob.y);
        }
    }
}

extern "C" void kernel_launch(void* const* d_in, const int* in_sizes, int n_in,
                              void* d_out, int out_size, void* d_ws, size_t ws_size,
                              hipStream_t stream)
{
    (void)in_sizes; (void)n_in; (void)out_size; (void)ws_size;
    const float* x         = (const float*)d_in[0];
    const float* lam_ri    = (const float*)d_in[1];
    const float* P_ri      = (const float*)d_in[2];
    const float* B_ri      = (const float*)d_in[3];
    const float* C_ri      = (const float*)d_in[4];
    const float* Dp        = (const float*)d_in[5];
    const float* log_delta = (const float*)d_in[6];
    float* y = (float*)d_out;

    float2* Kf = (float2*)d_ws;   // DD * LL * 8B = 8 MB

    s4_cauchy_kf<<<dim3(4, DD), 256, 0, stream>>>(lam_ri, P_ri, B_ri, C_ri, Dp, log_delta, Kf);
    s4_fftconv<<<dim3(BB*DD/4), 256, 0, stream>>>(x, Kf, y);
}